// Round 13
// baseline (914.635 us; speedup 1.0000x reference)
//
#include <hip/hip_runtime.h>
#include <math.h>

// ---------------- problem constants (match reference) ----------------
#define N_NODES 20000
#define N_EDGES 160000
#define G_GRAPHS 64
#define H_DIM 512
#define RH_DIM 128
#define NE_EXP 4
#define P_ROWS 20096   // 157 * 128, padded row count for GEMM tiles
#define EH_BLOCKS 64   // edge-histogram partial blocks
#define WSZ (512 * 512)

// ================= bf16 helpers =================
typedef __attribute__((ext_vector_type(8))) short bf16x8;
typedef __attribute__((ext_vector_type(4))) float f32x4;

__device__ __forceinline__ ushort f2bf(float f) {
    uint u = __float_as_uint(f);
    return (ushort)((u + 0x7FFFu + ((u >> 16) & 1u)) >> 16);  // round-to-nearest-even
}
__device__ __forceinline__ float bf2f(ushort h) {
    return __uint_as_float(((uint)h) << 16);
}

__device__ __forceinline__ void async_copy16(const void* g, void* l) {
    __builtin_amdgcn_global_load_lds(
        (__attribute__((address_space(1))) void*)g,
        (__attribute__((address_space(3))) void*)l, 16, 0, 0);
}

// ---- T1 bijective XCD swizzle (m204) ----
__device__ __forceinline__ int xcd_swizzle(int orig, int nwg) {
    const int q = nwg >> 3, r = nwg & 7;
    const int xcd = orig & 7, sid = orig >> 3;
    return (xcd < r ? xcd * (q + 1) : r * (q + 1) + (xcd - r) * q) + sid;
}

// ================= grouped expert GEMM (L0/L1; NE2 experts per launch) ======
// PROVEN kernel: 128x128 tile, 2-phase pipeline, vmcnt(4), 32KB LDS.
// EPI 0: out bf16(relu?(v+bias))
template<bool RELU, int NE2>
__global__ __launch_bounds__(256)
void gemm_grp(const ushort* __restrict__ A1, size_t a1es,
              const ushort* __restrict__ W1, size_t w1es,
              const ushort* __restrict__ A2, size_t a2es,
              const ushort* __restrict__ W2, size_t w2es,
              const float* __restrict__ bias, size_t bes,
              ushort* __restrict__ out0, size_t oes)
{
    __shared__ char smem[32768];   // 2 bufs x (A 8KB | B 8KB)
    const int tid = threadIdx.x;
    const int w = tid >> 6, lane = tid & 63;

    const int wgid = xcd_swizzle(blockIdx.x, gridDim.x);
    const int m0 = (wgid / (4 * NE2)) * 128;
    const int rem = wgid % (4 * NE2);
    const int e  = rem % NE2;
    const int n0 = (rem / NE2) * 128;

    const ushort* __restrict__ A1e = A1 + (size_t)e * a1es;
    const ushort* __restrict__ W1e = W1 + (size_t)e * w1es;
    const ushort* __restrict__ A2e = A2 + (size_t)e * a2es;
    const ushort* __restrict__ W2e = W2 + (size_t)e * w2es;
    const float*  __restrict__ be  = bias + (size_t)e * bes;
    ushort* __restrict__ oe = out0 + (size_t)e * oes;

    f32x4 acc[4][4];
#pragma unroll
    for (int i = 0; i < 4; ++i)
#pragma unroll
        for (int j = 0; j < 4; ++j) acc[i][j] = (f32x4){0.f, 0.f, 0.f, 0.f};

    const int srow = lane >> 2, schk = lane & 3;
    const int wr = w >> 1, wc = w & 1;
    const int row16 = lane & 15;
    const uint koffB = (uint)(lane >> 4) * 16u;
    const uint aoff0 = (uint)(wr * 64 + row16) * 64u + koffB;
    const uint boff0 = 8192u + (uint)(wc * 64 + row16) * 64u + koffB;

    auto stage = [&](int buf, int t) {
        const ushort* __restrict__ A  = (t < 16) ? A1e : A2e;
        const ushort* __restrict__ Wt = (t < 16) ? W1e : W2e;
        const int kt = (t & 15) * 32;
        char* base = smem + buf * 16384;
#pragma unroll
        for (int c = 0; c < 2; ++c) {
            const int rb = c * 64 + w * 16;   // wave-uniform LDS row base
            async_copy16(A  + (size_t)(m0 + rb + srow) * 512 + kt + schk * 8, base + rb * 64);
            async_copy16(Wt + (size_t)(n0 + rb + srow) * 512 + kt + schk * 8, base + 8192 + rb * 64);
        }
    };
    auto compute = [&](int buf) {
        const char* base = smem + buf * 16384;
        bf16x8 af[4], bfr[4];
#pragma unroll
        for (int i = 0; i < 4; ++i) af[i] = *(const bf16x8*)(base + aoff0 + i * 1024);
#pragma unroll
        for (int j = 0; j < 4; ++j) bfr[j] = *(const bf16x8*)(base + boff0 + j * 1024);
#pragma unroll
        for (int i = 0; i < 4; ++i)
#pragma unroll
            for (int j = 0; j < 4; ++j)
                acc[i][j] = __builtin_amdgcn_mfma_f32_16x16x32_bf16(af[i], bfr[j], acc[i][j], 0, 0, 0);
    };

    // 2-phase pipeline (proven R4-R12)
    stage(0, 0);
    for (int t = 0; t < 31; ++t) {
        stage((t + 1) & 1, t + 1);
        asm volatile("s_waitcnt vmcnt(4)" ::: "memory");
        __builtin_amdgcn_s_barrier();
        compute(t & 1);
        __builtin_amdgcn_s_barrier();
    }
    asm volatile("s_waitcnt vmcnt(0)" ::: "memory");
    __builtin_amdgcn_s_barrier();
    compute(1);

    // epilogue: C/D layout col = lane&15, row = (lane>>4)*4 + q
#pragma unroll
    for (int i = 0; i < 4; ++i) {
        const int r0 = m0 + wr * 64 + i * 16 + (lane >> 4) * 4;
#pragma unroll
        for (int j = 0; j < 4; ++j) {
            const int c = n0 + wc * 64 + j * 16 + row16;
            const float bj = be[c];
#pragma unroll
            for (int q2 = 0; q2 < 4; ++q2) {
                float v = acc[i][j][q2] + bj;
                if (RELU) v = fmaxf(v, 0.f);
                oe[(size_t)(r0 + q2) * 512 + c] = f2bf(v);
            }
        }
    }
}

// ================= L2 GEMM: row-compacted (top-2 sparsity) ==================
// Per pair dispatch: 4 local lists (e_local 0..1 x plane 0..1). Only rows
// where expert is selected. Same PROVEN 2-phase sync skeleton; only
// addressing differs (per-lane gathered global source for A; dense B).
// Output: planes[pl][r][c] = bf16(weights[r*4+eg] * (v + bias)).
__global__ __launch_bounds__(256)
void gemm_l2(const ushort* __restrict__ A1, size_t a1es,   // agge (pair-wide)
             const ushort* __restrict__ W1, size_t w1es,   // Wr2 base of pair
             const ushort* __restrict__ A2, size_t a2es,   // zBe (pair-wide)
             const ushort* __restrict__ W2, size_t w2es,   // Wo2 base of pair
             const float* __restrict__ bias, size_t bes,   // br2 base of pair
             const float* __restrict__ weights4,
             const int* __restrict__ lists, const int* __restrict__ cnt8,
             int egbase, ushort* __restrict__ planes)
{
    __shared__ char smem[32768];
    const int tid = threadIdx.x;
    const int w = tid >> 6, lane = tid & 63;

    const int wgid = xcd_swizzle(blockIdx.x, gridDim.x);
    const int m0 = (wgid / 16) * 128;
    const int rem = wgid % 16;
    const int li = rem & 3;            // local list: e_local = li>>1, plane = li&1
    const int n0 = (rem >> 2) * 128;
    const int el = li >> 1, pl = li & 1;
    const int eg = egbase + el;
    const int lid = eg * 2 + pl;
    const int cnt = cnt8[lid];
    if (m0 >= cnt) return;             // uniform per block; no barrier before this
    const int* __restrict__ idxl = lists + (size_t)lid * N_NODES;

    const ushort* __restrict__ A1e = A1 + (size_t)el * a1es;
    const ushort* __restrict__ W1e = W1 + (size_t)el * w1es;
    const ushort* __restrict__ A2e = A2 + (size_t)el * a2es;
    const ushort* __restrict__ W2e = W2 + (size_t)el * w2es;
    const float*  __restrict__ be  = bias + (size_t)el * bes;

    f32x4 acc[4][4];
#pragma unroll
    for (int i = 0; i < 4; ++i)
#pragma unroll
        for (int j = 0; j < 4; ++j) acc[i][j] = (f32x4){0.f, 0.f, 0.f, 0.f};

    const int srow = lane >> 2, schk = lane & 3;
    const int wr = w >> 1, wc = w & 1;
    const int row16 = lane & 15;
    const uint koffB = (uint)(lane >> 4) * 16u;
    const uint aoff0 = (uint)(wr * 64 + row16) * 64u + koffB;
    const uint boff0 = 8192u + (uint)(wc * 64 + row16) * 64u + koffB;

    // per-thread staged A rows (2 slots), gathered via list; clamp to valid
    size_t arow[2];
#pragma unroll
    for (int c = 0; c < 2; ++c) {
        int slot = m0 + c * 64 + w * 16 + srow;
        slot = (slot < cnt) ? slot : (cnt - 1);
        arow[c] = (size_t)idxl[slot] * 512 + schk * 8;
    }

    auto stage = [&](int buf, int t) {
        const ushort* __restrict__ A  = (t < 16) ? A1e : A2e;
        const ushort* __restrict__ Wt = (t < 16) ? W1e : W2e;
        const int kt = (t & 15) * 32;
        char* base = smem + buf * 16384;
#pragma unroll
        for (int c = 0; c < 2; ++c) {
            const int rb = c * 64 + w * 16;   // wave-uniform LDS dest (linear)
            async_copy16(A + arow[c] + kt, base + rb * 64);  // per-lane gathered source
            async_copy16(Wt + (size_t)(n0 + rb + srow) * 512 + kt + schk * 8, base + 8192 + rb * 64);
        }
    };
    auto compute = [&](int buf) {
        const char* base = smem + buf * 16384;
        bf16x8 af[4], bfr[4];
#pragma unroll
        for (int i = 0; i < 4; ++i) af[i] = *(const bf16x8*)(base + aoff0 + i * 1024);
#pragma unroll
        for (int j = 0; j < 4; ++j) bfr[j] = *(const bf16x8*)(base + boff0 + j * 1024);
#pragma unroll
        for (int i = 0; i < 4; ++i)
#pragma unroll
            for (int j = 0; j < 4; ++j)
                acc[i][j] = __builtin_amdgcn_mfma_f32_16x16x32_bf16(af[i], bfr[j], acc[i][j], 0, 0, 0);
    };

    // identical proven 2-phase skeleton
    stage(0, 0);
    for (int t = 0; t < 31; ++t) {
        stage((t + 1) & 1, t + 1);
        asm volatile("s_waitcnt vmcnt(4)" ::: "memory");
        __builtin_amdgcn_s_barrier();
        compute(t & 1);
        __builtin_amdgcn_s_barrier();
    }
    asm volatile("s_waitcnt vmcnt(0)" ::: "memory");
    __builtin_amdgcn_s_barrier();
    compute(1);

    // epilogue: scatter to plane[pl] at original row; guard slot < cnt
    ushort* __restrict__ plane = planes + (size_t)pl * ((size_t)P_ROWS * H_DIM);
#pragma unroll
    for (int i = 0; i < 4; ++i) {
        const int s0 = m0 + wr * 64 + i * 16 + (lane >> 4) * 4;
#pragma unroll
        for (int q2 = 0; q2 < 4; ++q2) {
            const int s = s0 + q2;
            if (s >= cnt) continue;
            const int r = idxl[s];
            const float wrow = weights4[(size_t)r * 4 + eg];
#pragma unroll
            for (int j = 0; j < 4; ++j) {
                const int c = n0 + wc * 64 + j * 16 + row16;
                const float v = acc[i][j][q2] + be[c];
                plane[(size_t)r * 512 + c] = f2bf(v * wrow);
            }
        }
    }
}

// ================= encoder/router bf16x3 GEMM (2-phase, proven) =============
// EPI 4: hi/lo bf16 split -> out0/out1 ; EPI 5: out0 fp32
template<int NPASS, int EPI, int NBN>
__global__ __launch_bounds__(256)
void gemm_mfma(const ushort* __restrict__ A0, const ushort* __restrict__ W0,
               const ushort* __restrict__ A1p, const ushort* __restrict__ W1p,
               const ushort* __restrict__ A2p, const ushort* __restrict__ W2p,
               const float* __restrict__ bias,
               void* __restrict__ out0, void* __restrict__ out1, int Ncols)
{
    __shared__ char smem[32768];
    const int tid = threadIdx.x;
    const int w = tid >> 6, lane = tid & 63;

    const int wgid = xcd_swizzle(blockIdx.x, gridDim.x);
    const int m0 = (wgid / NBN) * 128;
    const int n0 = (wgid % NBN) * 128;

    f32x4 acc[4][4];
#pragma unroll
    for (int i = 0; i < 4; ++i)
#pragma unroll
        for (int j = 0; j < 4; ++j) acc[i][j] = (f32x4){0.f, 0.f, 0.f, 0.f};

    const int srow = lane >> 2, schk = lane & 3;
    const int wr = w >> 1, wc = w & 1;
    const int row16 = lane & 15;
    const uint koffB = (uint)(lane >> 4) * 16u;
    const uint aoff0 = (uint)(wr * 64 + row16) * 64u + koffB;
    const uint boff0 = 8192u + (uint)(wc * 64 + row16) * 64u + koffB;

    const int NT = NPASS * 16;
    auto Asel = [&](int t) -> const ushort* { return (t < 16) ? A0 : ((t < 32) ? A1p : A2p); };
    auto Wsel = [&](int t) -> const ushort* { return (t < 16) ? W0 : ((t < 32) ? W1p : W2p); };

    auto stage = [&](int buf, int t) {
        const ushort* __restrict__ A  = Asel(t);
        const ushort* __restrict__ Wt = Wsel(t);
        const int kt = (t & 15) * 32;
        char* base = smem + buf * 16384;
#pragma unroll
        for (int c = 0; c < 2; ++c) {
            const int rb = c * 64 + w * 16;
            async_copy16(A  + (size_t)(m0 + rb + srow) * 512 + kt + schk * 8, base + rb * 64);
            async_copy16(Wt + (size_t)(n0 + rb + srow) * 512 + kt + schk * 8, base + 8192 + rb * 64);
        }
    };
    auto compute = [&](int buf) {
        const char* base = smem + buf * 16384;
        bf16x8 af[4], bfr[4];
#pragma unroll
        for (int i = 0; i < 4; ++i) af[i] = *(const bf16x8*)(base + aoff0 + i * 1024);
#pragma unroll
        for (int j = 0; j < 4; ++j) bfr[j] = *(const bf16x8*)(base + boff0 + j * 1024);
#pragma unroll
        for (int i = 0; i < 4; ++i)
#pragma unroll
            for (int j = 0; j < 4; ++j)
                acc[i][j] = __builtin_amdgcn_mfma_f32_16x16x32_bf16(af[i], bfr[j], acc[i][j], 0, 0, 0);
    };

    stage(0, 0);
    for (int t = 0; t < NT - 1; ++t) {
        stage((t + 1) & 1, t + 1);
        asm volatile("s_waitcnt vmcnt(4)" ::: "memory");
        __builtin_amdgcn_s_barrier();
        compute(t & 1);
        __builtin_amdgcn_s_barrier();
    }
    asm volatile("s_waitcnt vmcnt(0)" ::: "memory");
    __builtin_amdgcn_s_barrier();
    compute((NT - 1) & 1);

#pragma unroll
    for (int i = 0; i < 4; ++i) {
        const int r0 = m0 + wr * 64 + i * 16 + (lane >> 4) * 4;
#pragma unroll
        for (int j = 0; j < 4; ++j) {
            const int c = n0 + wc * 64 + j * 16 + row16;
            const float bj = (EPI == 5) ? 0.f : bias[c];
#pragma unroll
            for (int q2 = 0; q2 < 4; ++q2) {
                const int r = r0 + q2;
                float v = acc[i][j][q2] + bj;
                if (EPI == 4) {
                    const ushort hi = f2bf(v);
                    const ushort lo = f2bf(v - bf2f(hi));
                    ((ushort*)out0)[(size_t)r * Ncols + c] = hi;
                    ((ushort*)out1)[(size_t)r * Ncols + c] = lo;
                } else {
                    ((float*)out0)[(size_t)r * Ncols + c] = v;
                }
            }
        }
    }
}

// out[r,c] = plane0[r,c] + plane1[r,c]  (2 cols/thread)
__global__ __launch_bounds__(256)
void reduce2_kernel(const uint* __restrict__ p0, const uint* __restrict__ p1,
                    float2* __restrict__ out)
{
    const size_t idx = (size_t)blockIdx.x * 256 + threadIdx.x;  // < N_NODES*256
    const uint a = p0[idx], b = p1[idx];
    float lo = bf2f((ushort)(a & 0xffffu)) + bf2f((ushort)(b & 0xffffu));
    float hi = bf2f((ushort)(a >> 16)) + bf2f((ushort)(b >> 16));
    out[idx] = make_float2(lo, hi);
}

// build 8 compaction lists: row r -> (e_min, plane0) and (e_max, plane1).
// two-level: LDS slot reservation + one global atomicAdd per bin per block.
__global__ __launch_bounds__(256)
void select_kernel(const float* __restrict__ weights, int* __restrict__ cnt8,
                   int* __restrict__ lists)
{
    __shared__ int lcnt[8];
    __shared__ int lbase[8];
    const int tid = threadIdx.x;
    if (tid < 8) lcnt[tid] = 0;
    __syncthreads();
    const int r = blockIdx.x * 256 + tid;
    int e1 = -1, e2 = -1, s1 = 0, s2 = 0;
    if (r < N_NODES) {
#pragma unroll
        for (int c = 0; c < 4; ++c) {
            if (weights[(size_t)r * 4 + c] > 0.f) {
                if (e1 < 0) e1 = c; else e2 = c;
            }
        }
        s1 = atomicAdd(&lcnt[e1 * 2 + 0], 1);
        s2 = atomicAdd(&lcnt[e2 * 2 + 1], 1);
    }
    __syncthreads();
    if (tid < 8) lbase[tid] = atomicAdd(&cnt8[tid], lcnt[tid]);
    __syncthreads();
    if (r < N_NODES) {
        lists[(size_t)(e1 * 2 + 0) * N_NODES + lbase[e1 * 2 + 0] + s1] = r;
        lists[(size_t)(e2 * 2 + 1) * N_NODES + lbase[e2 * 2 + 1] + s2] = r;
    }
}

// t1 = relu(x[:,4:10] @ enc_W1 + enc_b1), split into bf16 hi+lo; zero pad rows
__global__ void encoder1_kernel(const float* __restrict__ x, const float* __restrict__ W1,
                                const float* __restrict__ b1,
                                ushort* __restrict__ t1hi, ushort* __restrict__ t1lo)
{
    const int idx = blockIdx.x * blockDim.x + threadIdx.x;
    if (idx >= P_ROWS * H_DIM) return;
    const int i = idx / H_DIM, j = idx - i * H_DIM;
    float v = 0.f;
    if (i < N_NODES) {
        const float* xr = &x[i * 16 + 4];
        v = b1[j];
#pragma unroll
        for (int k = 0; k < 6; ++k) v = fmaf(xr[k], W1[k * H_DIM + j], v);
        v = fmaxf(v, 0.f);
    }
    const ushort hi = f2bf(v);
    t1hi[idx] = hi;
    t1lo[idx] = f2bf(v - bf2f(hi));
}

__global__ void zero_ints_kernel(int* __restrict__ p, int n)
{
    const int idx = blockIdx.x * blockDim.x + threadIdx.x;
    if (idx < n) p[idx] = 0;
}

__global__ void graph_bounds_kernel(const int* __restrict__ batch, int* __restrict__ gstart)
{
    const int g = threadIdx.x;
    if (g > G_GRAPHS) return;
    int lo = 0, hi = N_NODES;
    while (lo < hi) {
        const int mid = (lo + hi) >> 1;
        if (batch[mid] < g) lo = mid + 1; else hi = mid;
    }
    gstart[g] = lo;
}

__global__ __launch_bounds__(256)
void edge_hist_kernel(const int* __restrict__ src, const int* __restrict__ dst,
                      const int* __restrict__ batch,
                      int* __restrict__ part, int* __restrict__ deg)
{
    __shared__ int hist[G_GRAPHS];
    const int tid = threadIdx.x;
    if (tid < G_GRAPHS) hist[tid] = 0;
    __syncthreads();
    for (int e = blockIdx.x * 256 + tid; e < N_EDGES; e += EH_BLOCKS * 256) {
        atomicAdd(&deg[dst[e]], 1);
        atomicAdd(&hist[batch[src[e]]], 1);
    }
    __syncthreads();
    if (tid < G_GRAPHS) part[blockIdx.x * G_GRAPHS + tid] = hist[tid];
}

__global__ void stats_finalize_kernel(const int* __restrict__ gstart, const int* __restrict__ part,
                                      float* __restrict__ f_norm, float* __restrict__ size_norm)
{
    const int g = threadIdx.x;  // exactly 64
    const float nn = fmaxf((float)(gstart[g + 1] - gstart[g]), 1.0f);
    int ec = 0;
#pragma unroll 8
    for (int b = 0; b < EH_BLOCKS; ++b) ec += part[b * G_GRAPHS + g];
    const float ee = (float)ec;
    const float ln = logf(nn);
    const float le = log1pf(ee);
    float s0 = ln, s1 = le;
#pragma unroll
    for (int o = 32; o > 0; o >>= 1) { s0 += __shfl_xor(s0, o); s1 += __shfl_xor(s1, o); }
    const float m0 = s0 / 64.f, m1 = s1 / 64.f;
    const float d0 = ln - m0, d1 = le - m1;
    float v0 = d0 * d0, v1 = d1 * d1;
#pragma unroll
    for (int o = 32; o > 0; o >>= 1) { v0 += __shfl_xor(v0, o); v1 += __shfl_xor(v1, o); }
    const float sd0 = sqrtf(v0 / 64.f), sd1 = sqrtf(v1 / 64.f);
    float mn = ln, mx = ln;
#pragma unroll
    for (int o = 32; o > 0; o >>= 1) {
        mn = fminf(mn, __shfl_xor(mn, o));
        mx = fmaxf(mx, __shfl_xor(mx, o));
    }
    f_norm[g * 2 + 0] = d0 / (sd0 + 1e-6f);
    f_norm[g * 2 + 1] = d1 / (sd1 + 1e-6f);
    size_norm[g] = (ln - mn) / (mx - mn + 1e-6f);
}

__global__ void scan_kernel(const int* __restrict__ in, int* __restrict__ row_ptr,
                            int* __restrict__ cursor, int n)
{
    __shared__ int wsum[16];
    __shared__ int carry_s;
    const int tid = threadIdx.x;
    const int lane = tid & 63, wv = tid >> 6;
    if (tid == 0) carry_s = 0;
    __syncthreads();
    for (int base = 0; base < n; base += 1024) {
        const int idx = base + tid;
        const int v = (idx < n) ? in[idx] : 0;
        int x = v;
#pragma unroll
        for (int o = 1; o < 64; o <<= 1) { const int t = __shfl_up(x, o); if (lane >= o) x += t; }
        if (lane == 63) wsum[wv] = x;
        __syncthreads();
        const int carry = carry_s;
        if (wv == 0) {
            int y = (lane < 16) ? wsum[lane] : 0;
#pragma unroll
            for (int o = 1; o < 16; o <<= 1) { const int t = __shfl_up(y, o); if (lane >= o) y += t; }
            if (lane < 16) wsum[lane] = y;
        }
        __syncthreads();
        const int woff = (wv > 0) ? wsum[wv - 1] : 0;
        const int excl = x - v + woff + carry;
        if (idx < n) { row_ptr[idx] = excl; cursor[idx] = excl; }
        __syncthreads();
        if (tid == 0) carry_s = carry + wsum[15];
        __syncthreads();
    }
    if (tid == 0) row_ptr[n] = carry_s;
}

__global__ void scatter_kernel(const int* __restrict__ src, const int* __restrict__ dst,
                               int* __restrict__ cursor, int* __restrict__ csr_col)
{
    const int e = blockIdx.x * blockDim.x + threadIdx.x;
    if (e >= N_EDGES) return;
    const int d = dst[e];
    const int slot = atomicAdd(&cursor[d], 1);
    csr_col[slot] = src[e];
}

__global__ void sort_adj_kernel(const int* __restrict__ row_ptr, int* __restrict__ csr_col)
{
    const int i = blockIdx.x * blockDim.x + threadIdx.x;
    if (i >= N_NODES) return;
    const int b = row_ptr[i], e = row_ptr[i + 1];
    for (int p = b + 1; p < e; ++p) {
        const int key = csr_col[p];
        int q = p - 1;
        while (q >= b && csr_col[q] > key) { csr_col[q + 1] = csr_col[q]; --q; }
        csr_col[q + 1] = key;
    }
}

// agg[e][i,:] = sum over in-edges of z[e][src,:]
// wave-per-node, uint4 (16B/lane) loads; 4 nodes per 256-thr block. (proven)
__global__ __launch_bounds__(256)
void aggregate_bf16(const uint4* __restrict__ z4, const int* __restrict__ row_ptr,
                    const int* __restrict__ csr_col, uint4* __restrict__ agg4)
{
    const size_t es = (size_t)blockIdx.y * P_ROWS * 64;   // uint4s per expert
    const uint4* __restrict__ zz = z4 + es;
    uint4* __restrict__ aa = agg4 + es;
    const int i = blockIdx.x * 4 + (threadIdx.x >> 6);     // node (grid 5000x4 exact)
    const int lane = threadIdx.x & 63;
    const int b = row_ptr[i], e = row_ptr[i + 1];
    float acc[8];
#pragma unroll
    for (int k = 0; k < 8; ++k) acc[k] = 0.f;
    auto add8 = [&](uint4 v) {
        acc[0] += bf2f((ushort)(v.x & 0xffffu)); acc[1] += bf2f((ushort)(v.x >> 16));
        acc[2] += bf2f((ushort)(v.y & 0xffffu)); acc[3] += bf2f((ushort)(v.y >> 16));
        acc[4] += bf2f((ushort)(v.z & 0xffffu)); acc[5] += bf2f((ushort)(v.z >> 16));
        acc[6] += bf2f((ushort)(v.w & 0xffffu)); acc[7] += bf2f((ushort)(v.w >> 16));
    };
    int p = b;
    for (; p + 2 <= e; p += 2) {
        const uint4 v0 = zz[(size_t)csr_col[p] * 64 + lane];
        const uint4 v1 = zz[(size_t)csr_col[p + 1] * 64 + lane];
        add8(v0);
        add8(v1);
    }
    if (p < e) add8(zz[(size_t)csr_col[p] * 64 + lane]);
    uint4 o;
    o.x = (uint)f2bf(acc[0]) | ((uint)f2bf(acc[1]) << 16);
    o.y = (uint)f2bf(acc[2]) | ((uint)f2bf(acc[3]) << 16);
    o.z = (uint)f2bf(acc[4]) | ((uint)f2bf(acc[5]) << 16);
    o.w = (uint)f2bf(acc[6]) | ((uint)f2bf(acc[7]) << 16);
    aa[(size_t)i * 64 + lane] = o;
}

// one 512x512 matrix per blockIdx.z: Wt[n][k] = bf16(W[k][n])
__global__ __launch_bounds__(256)
void transpose_f32_to_bf16(const float* __restrict__ W, ushort* __restrict__ Wt)
{
    __shared__ float tile[32][33];
    const float* Wm = W + (size_t)blockIdx.z * WSZ;
    ushort* Wtm = Wt + (size_t)blockIdx.z * WSZ;
    const int c0 = blockIdx.x * 32, r0 = blockIdx.y * 32;
    const int tc = threadIdx.x & 31, tr = threadIdx.x >> 5;
#pragma unroll
    for (int it = 0; it < 4; ++it)
        tile[tr + it * 8][tc] = Wm[(size_t)(r0 + tr + it * 8) * 512 + c0 + tc];
    __syncthreads();
#pragma unroll
    for (int it = 0; it < 4; ++it) {
        const int cr = tr + it * 8;
        Wtm[(size_t)(c0 + cr) * 512 + r0 + tc] = f2bf(tile[tc][cr]);
    }
}

// W [512][Nin] fp32 -> Wt hi/lo [Nin][512] bf16 (k-stride 512)
__global__ __launch_bounds__(256)
void transpose_split_kernel(const float* __restrict__ W, ushort* __restrict__ Whi,
                            ushort* __restrict__ Wlo, int Nin)
{
    __shared__ float tile[32][33];
    const int c0 = blockIdx.x * 32;
    const int r0 = blockIdx.y * 32;
    const int tc = threadIdx.x & 31, tr = threadIdx.x >> 5;
#pragma unroll
    for (int it = 0; it < 4; ++it)
        tile[tr + it * 8][tc] = W[(size_t)(r0 + tr + it * 8) * Nin + c0 + tc];
    __syncthreads();
#pragma unroll
    for (int it = 0; it < 4; ++it) {
        const int cr = tr + it * 8;
        const float v = tile[tc][cr];
        const ushort hi = f2bf(v);
        Whi[(size_t)(c0 + cr) * 512 + r0 + tc] = hi;
        Wlo[(size_t)(c0 + cr) * 512 + r0 + tc] = f2bf(v - bf2f(hi));
    }
}

// router tail (fp32)
__global__ __launch_bounds__(128)
void router_kernel(const float* __restrict__ rtmp, const int* __restrict__ batch,
                   const float* __restrict__ rW1, const float* __restrict__ rb1,
                   const float* __restrict__ lng, const float* __restrict__ lnb,
                   const float* __restrict__ rW2, const float* __restrict__ rb2,
                   const float* __restrict__ centers,
                   const float* __restrict__ f_norm, const float* __restrict__ size_norm,
                   float* __restrict__ weights)
{
    const int i = blockIdx.x;
    const int j = threadIdx.x;
    const int g = batch[i];
    const float f0 = f_norm[g * 2], f1 = f_norm[g * 2 + 1];
    float r = rtmp[(size_t)i * RH_DIM + j]
            + f0 * rW1[512 * RH_DIM + j] + f1 * rW1[513 * RH_DIM + j] + rb1[j];

    __shared__ float part[2];
    __shared__ float rbuf[RH_DIM];
    __shared__ float lbuf[4];
    const int lane = j & 63, wv = j >> 6;

    float s = r;
#pragma unroll
    for (int o = 32; o > 0; o >>= 1) s += __shfl_xor(s, o);
    if (lane == 0) part[wv] = s;
    __syncthreads();
    const float mean = (part[0] + part[1]) / 128.f;
    __syncthreads();
    const float d = r - mean;
    float v = d * d;
#pragma unroll
    for (int o = 32; o > 0; o >>= 1) v += __shfl_xor(v, o);
    if (lane == 0) part[wv] = v;
    __syncthreads();
    const float var = (part[0] + part[1]) / 128.f;
    const float rn = d / sqrtf(var + 1e-5f) * lng[j] + lnb[j];
    rbuf[j] = fmaxf(rn, 0.f);
    __syncthreads();

    if (j < 4) {
        float acc = rb2[j];
        for (int t = 0; t < RH_DIM; ++t) acc = fmaf(rbuf[t], rW2[t * 4 + j], acc);
        const float sn = size_norm[g];
        const float dd = sn - centers[j];
        lbuf[j] = 0.7f * acc + 0.3f * (-(dd * dd));
    }
    __syncthreads();
    if (j == 0) {
        float p[4];
        const float mx = fmaxf(fmaxf(lbuf[0], lbuf[1]), fmaxf(lbuf[2], lbuf[3]));
#pragma unroll
        for (int c = 0; c < 4; ++c) p[c] = expf(lbuf[c] - mx);
        const float ssum = p[0] + p[1] + p[2] + p[3];
#pragma unroll
        for (int c = 0; c < 4; ++c) p[c] /= ssum;
        int i1 = 0;
#pragma unroll
        for (int c = 1; c < 4; ++c) if (p[c] > p[i1]) i1 = c;
        int i2 = -1;
#pragma unroll
        for (int c = 0; c < 4; ++c) {
            if (c == i1) continue;
            if (i2 < 0 || p[c] > p[i2]) i2 = c;
        }
        const float vs = p[i1] + p[i2] + 1e-8f;
        float wout[4] = {0.f, 0.f, 0.f, 0.f};
        wout[i1] = p[i1] / vs;
        wout[i2] = p[i2] / vs;
#pragma unroll
        for (int c = 0; c < 4; ++c) weights[(size_t)i * 4 + c] = wout[c];
    }
}

extern "C" void kernel_launch(void* const* d_in, const int* in_sizes, int n_in,
                              void* d_out, int out_size, void* d_ws, size_t ws_size,
                              hipStream_t stream)
{
    const float* x       = (const float*)d_in[0];
    const int*   ei      = (const int*)d_in[1];
    const int*   batch   = (const int*)d_in[2];
    const float* enc_W1  = (const float*)d_in[4];
    const float* enc_b1  = (const float*)d_in[5];
    const float* enc_W2  = (const float*)d_in[6];
    const float* enc_b2  = (const float*)d_in[7];
    const float* r_W1    = (const float*)d_in[8];
    const float* r_b1    = (const float*)d_in[9];
    const float* ln_g    = (const float*)d_in[10];
    const float* ln_b    = (const float*)d_in[11];
    const float* r_W2    = (const float*)d_in[12];
    const float* r_b2    = (const float*)d_in[13];
    const float* centers = (const float*)d_in[14];
    const float* W_rel   = (const float*)d_in[15];
    const float* b_rel   = (const float*)d_in[16];
    const float* W_root  = (const float*)d_in[17];
    const int* src = ei;
    const int* dst = ei + N_EDGES;
    float* out = (float*)d_out;

    const size_t PF = (size_t)P_ROWS * H_DIM;
    const size_t PF2 = PF * 2;

    char* wsp = (char*)d_ws;
    size_t off = 0;
    auto alloc = [&](size_t bytes) -> char* {
        char* p = wsp + off;
        off = (off + bytes + 255) & ~(size_t)255;
        return p;
    };
    // region1: t1hi|t1lo  -> later planes[0]|planes[1] (L2 output planes)
    char* region1 = alloc(PF * 4);
    ushort* t1hi = (ushort*)region1;
    ushort* t1lo = (ushort*)(region1 + PF * 2);
    ushort* planes = (ushort*)region1;
    // region2: h_hi|h_lo (alive through both pairs' L0)
    char* region2 = alloc(PF * 4);
    ushort* h_hi = (ushort*)region2;
    ushort* h_lo = (ushort*)(region2 + PF * 2);
    // z/agg buffers (pair-wide); rtmp fp32 aliases zA start (dead before expert L0)
    char* B_zA = alloc(PF2 * 2);
    ushort* zAe = (ushort*)B_zA;
    float*  rtmp = (float*)B_zA;
    char* B_zB = alloc(PF2 * 2);
    ushort* zBe = (ushort*)B_zB;
    char* B_ag = alloc(PF2 * 2);
    ushort* agge = (ushort*)B_ag;
    ushort* aggH16 = (ushort*)alloc(PF * 2);
    ushort* Wt_rel16  = (ushort*)alloc((size_t)12 * WSZ * 2);
    ushort* Wt_root16 = (ushort*)alloc((size_t)12 * WSZ * 2);
    ushort* W2t_hi = (ushort*)alloc((size_t)WSZ * 2);
    ushort* W2t_lo = (ushort*)alloc((size_t)WSZ * 2);
    ushort* rW1t_hi = (ushort*)alloc((size_t)128 * 512 * 2);
    ushort* rW1t_lo = (ushort*)alloc((size_t)128 * 512 * 2);
    float*  weights = (float*)alloc((size_t)P_ROWS * 4 * 4);
    int* deg     = (int*)alloc((size_t)(N_NODES + 8) * 4);
    int* cnt8    = deg + N_NODES;
    int* gstart  = (int*)alloc((size_t)(G_GRAPHS + 1) * 4);
    int* part    = (int*)alloc((size_t)EH_BLOCKS * G_GRAPHS * 4);
    int* row_ptr = (int*)alloc((size_t)(N_NODES + 1) * 4);
    int* cursor  = (int*)alloc((size_t)N_NODES * 4);
    int* csr_col = (int*)alloc((size_t)N_EDGES * 4);
    int* lists   = (int*)alloc((size_t)8 * N_NODES * 4);
    float* f_norm    = (float*)alloc((size_t)G_GRAPHS * 2 * 4);
    float* size_norm = (float*)alloc((size_t)G_GRAPHS * 4);
    (void)in_sizes; (void)n_in; (void)out_size; (void)ws_size;

    const int enc_nwg  = 4 * (P_ROWS / 128);   // 628
    const int rtr_nwg  = 1 * (P_ROWS / 128);   // 157
    const int grp_nwg2 = 8 * (P_ROWS / 128);   // 1256 (pair, L0/L1)
    const int l2_nwg   = 16 * (P_ROWS / 128);  // 2512 (4 lists x 4 n), early-exit
    const dim3 tr_grid(16, 16, 12);
    const dim3 agg_grid1(N_NODES / 4, 1);
    const dim3 agg_grid2(N_NODES / 4, 2);

    // 0) zero deg+cnt8 + one-time weight transposes/splits
    zero_ints_kernel<<<(N_NODES + 8 + 255) / 256, 256, 0, stream>>>(deg, N_NODES + 8);
    transpose_f32_to_bf16<<<tr_grid, 256, 0, stream>>>(W_rel, Wt_rel16);
    transpose_f32_to_bf16<<<tr_grid, 256, 0, stream>>>(W_root, Wt_root16);
    transpose_split_kernel<<<dim3(16, 16), 256, 0, stream>>>(enc_W2, W2t_hi, W2t_lo, 512);
    transpose_split_kernel<<<dim3(4, 16), 256, 0, stream>>>(r_W1, rW1t_hi, rW1t_lo, 128);
    // 1) graph stats (contention-free)
    graph_bounds_kernel<<<1, 128, 0, stream>>>(batch, gstart);
    edge_hist_kernel<<<EH_BLOCKS, 256, 0, stream>>>(src, dst, batch, part, deg);
    stats_finalize_kernel<<<1, 64, 0, stream>>>(gstart, part, f_norm, size_norm);
    // 2) encoder: t1 (split) then h = t1@W2 via bf16x3 -> h_hi/h_lo
    encoder1_kernel<<<(P_ROWS * H_DIM + 255) / 256, 256, 0, stream>>>(x, enc_W1, enc_b1, t1hi, t1lo);
    gemm_mfma<3, 4, 4><<<enc_nwg, 256, 0, stream>>>(
        t1hi, W2t_hi, t1hi, W2t_lo, t1lo, W2t_hi, enc_b2, h_hi, h_lo, 512);
    // 3) router: rtmp = h@rW1 via bf16x3 (t1 region dead now)
    gemm_mfma<3, 5, 1><<<rtr_nwg, 256, 0, stream>>>(
        h_hi, rW1t_hi, h_hi, rW1t_lo, h_lo, rW1t_hi, nullptr, rtmp, nullptr, 128);
    router_kernel<<<N_NODES, 128, 0, stream>>>(rtmp, batch, r_W1, r_b1, ln_g, ln_b,
                                               r_W2, r_b2, centers, f_norm, size_norm, weights);
    // 3b) top-2 selection lists (8 lists, deterministic output per row)
    select_kernel<<<(N_NODES + 255) / 256, 256, 0, stream>>>(weights, cnt8, lists);
    // 4) CSR build (deterministic: sorted adjacency)
    scan_kernel<<<1, 1024, 0, stream>>>(deg, row_ptr, cursor, N_NODES);
    scatter_kernel<<<(N_EDGES + 255) / 256, 256, 0, stream>>>(src, dst, cursor, csr_col);
    sort_adj_kernel<<<(N_NODES + 255) / 256, 256, 0, stream>>>(row_ptr, csr_col);
    // 5) shared layer-0 aggregation
    aggregate_bf16<<<agg_grid1, 256, 0, stream>>>((const uint4*)h_hi, row_ptr, csr_col,
                                                  (uint4*)aggH16);

    // 6) experts (pair path; L0/L1 dense, L2 row-compacted)
    const size_t WES = (size_t)3 * WSZ;   // expert stride in Wt buffers
    const size_t BES = (size_t)3 * 512;   // expert stride in b_rel
    for (int p = 0; p < 2; ++p) {
        const size_t eb = (size_t)(p * 2);
        const ushort* WrP = Wt_rel16  + eb * WES;
        const ushort* WoP = Wt_root16 + eb * WES;
        const float*  brP = b_rel + eb * BES;
        gemm_grp<true, 2><<<grp_nwg2, 256, 0, stream>>>(
            aggH16, 0, WrP, WES, h_hi, 0, WoP, WES, brP, BES, zAe, PF);
        aggregate_bf16<<<agg_grid2, 256, 0, stream>>>((const uint4*)zAe, row_ptr, csr_col,
                                                      (uint4*)agge);
        gemm_grp<true, 2><<<grp_nwg2, 256, 0, stream>>>(
            agge, PF, WrP + WSZ, WES, zAe, PF, WoP + WSZ, WES, brP + 512, BES, zBe, PF);
        aggregate_bf16<<<agg_grid2, 256, 0, stream>>>((const uint4*)zBe, row_ptr, csr_col,
                                                      (uint4*)agge);
        gemm_l2<<<l2_nwg, 256, 0, stream>>>(
            agge, PF, WrP + 2 * WSZ, WES, zBe, PF, WoP + 2 * WSZ, WES, brP + 1024, BES,
            weights, lists, cnt8, (int)eb, planes);
    }
    // 7) out = plane0 + plane1
    reduce2_kernel<<<N_NODES, 256, 0, stream>>>((const uint*)planes,
                                                (const uint*)(planes + PF), (float2*)out);
}

// Round 14
// 837.721 us; speedup vs baseline: 1.0918x; 1.0918x over previous
//
#include <hip/hip_runtime.h>
#include <math.h>

// ---------------- problem constants (match reference) ----------------
#define N_NODES 20000
#define N_EDGES 160000
#define G_GRAPHS 64
#define H_DIM 512
#define RH_DIM 128
#define NE_EXP 4
#define P_ROWS 20096   // 157 * 128, padded row count for GEMM tiles
#define EH_BLOCKS 64   // edge-histogram partial blocks
#define WSZ (512 * 512)

// ================= bf16 helpers =================
typedef __attribute__((ext_vector_type(8))) short bf16x8;
typedef __attribute__((ext_vector_type(4))) float f32x4;

__device__ __forceinline__ ushort f2bf(float f) {
    uint u = __float_as_uint(f);
    return (ushort)((u + 0x7FFFu + ((u >> 16) & 1u)) >> 16);  // round-to-nearest-even
}
__device__ __forceinline__ float bf2f(ushort h) {
    return __uint_as_float(((uint)h) << 16);
}

__device__ __forceinline__ void async_copy16(const void* g, void* l) {
    __builtin_amdgcn_global_load_lds(
        (__attribute__((address_space(1))) void*)g,
        (__attribute__((address_space(3))) void*)l, 16, 0, 0);
}

// ---- T1 bijective XCD swizzle (m204) ----
__device__ __forceinline__ int xcd_swizzle(int orig, int nwg) {
    const int q = nwg >> 3, r = nwg & 7;
    const int xcd = orig & 7, sid = orig >> 3;
    return (xcd < r ? xcd * (q + 1) : r * (q + 1) + (xcd - r) * q) + sid;
}

// ================= grouped expert GEMM (NE2 experts per launch) =============
// PROVEN R6/R8/R10/R12 kernel: 128x128 tile, 2-phase pipeline, vmcnt(4),
// 32KB LDS, coalesced global_load_lds staging for BOTH A and B.
// EPI 0: out bf16(relu?(v+bias)) ; EPI 6: out bf16((v+bias)*wcol[r*4+e])
template<bool RELU, int EPI, int NE2>
__global__ __launch_bounds__(256)
void gemm_grp(const ushort* __restrict__ A1, size_t a1es,
              const ushort* __restrict__ W1, size_t w1es,
              const ushort* __restrict__ A2, size_t a2es,
              const ushort* __restrict__ W2, size_t w2es,
              const float* __restrict__ bias, size_t bes,
              const float* __restrict__ wcol,
              ushort* __restrict__ out0, size_t oes)
{
    __shared__ char smem[32768];   // 2 bufs x (A 8KB | B 8KB)
    const int tid = threadIdx.x;
    const int w = tid >> 6, lane = tid & 63;

    const int wgid = xcd_swizzle(blockIdx.x, gridDim.x);
    const int m0 = (wgid / (4 * NE2)) * 128;
    const int rem = wgid % (4 * NE2);
    const int e  = rem % NE2;
    const int n0 = (rem / NE2) * 128;

    const ushort* __restrict__ A1e = A1 + (size_t)e * a1es;
    const ushort* __restrict__ W1e = W1 + (size_t)e * w1es;
    const ushort* __restrict__ A2e = A2 + (size_t)e * a2es;
    const ushort* __restrict__ W2e = W2 + (size_t)e * w2es;
    const float*  __restrict__ be  = bias + (size_t)e * bes;
    ushort* __restrict__ oe = out0 + (size_t)e * oes;

    f32x4 acc[4][4];
#pragma unroll
    for (int i = 0; i < 4; ++i)
#pragma unroll
        for (int j = 0; j < 4; ++j) acc[i][j] = (f32x4){0.f, 0.f, 0.f, 0.f};

    const int srow = lane >> 2, schk = lane & 3;
    const int wr = w >> 1, wc = w & 1;
    const int row16 = lane & 15;
    const uint koffB = (uint)(lane >> 4) * 16u;
    const uint aoff0 = (uint)(wr * 64 + row16) * 64u + koffB;
    const uint boff0 = 8192u + (uint)(wc * 64 + row16) * 64u + koffB;

    auto stage = [&](int buf, int t) {
        const ushort* __restrict__ A  = (t < 16) ? A1e : A2e;
        const ushort* __restrict__ Wt = (t < 16) ? W1e : W2e;
        const int kt = (t & 15) * 32;
        char* base = smem + buf * 16384;
#pragma unroll
        for (int c = 0; c < 2; ++c) {
            const int rb = c * 64 + w * 16;   // wave-uniform LDS row base
            async_copy16(A  + (size_t)(m0 + rb + srow) * 512 + kt + schk * 8, base + rb * 64);
            async_copy16(Wt + (size_t)(n0 + rb + srow) * 512 + kt + schk * 8, base + 8192 + rb * 64);
        }
    };
    auto compute = [&](int buf) {
        const char* base = smem + buf * 16384;
        bf16x8 af[4], bfr[4];
#pragma unroll
        for (int i = 0; i < 4; ++i) af[i] = *(const bf16x8*)(base + aoff0 + i * 1024);
#pragma unroll
        for (int j = 0; j < 4; ++j) bfr[j] = *(const bf16x8*)(base + boff0 + j * 1024);
#pragma unroll
        for (int i = 0; i < 4; ++i)
#pragma unroll
            for (int j = 0; j < 4; ++j)
                acc[i][j] = __builtin_amdgcn_mfma_f32_16x16x32_bf16(af[i], bfr[j], acc[i][j], 0, 0, 0);
    };

    // 2-phase pipeline (T3 minimum + T4 counted vmcnt) — proven R4-R12
    stage(0, 0);
    for (int t = 0; t < 31; ++t) {
        stage((t + 1) & 1, t + 1);
        asm volatile("s_waitcnt vmcnt(4)" ::: "memory");
        __builtin_amdgcn_s_barrier();
        compute(t & 1);
        __builtin_amdgcn_s_barrier();
    }
    asm volatile("s_waitcnt vmcnt(0)" ::: "memory");
    __builtin_amdgcn_s_barrier();
    compute(1);

    // epilogue: C/D layout col = lane&15, row = (lane>>4)*4 + q
#pragma unroll
    for (int i = 0; i < 4; ++i) {
        const int r0 = m0 + wr * 64 + i * 16 + (lane >> 4) * 4;
#pragma unroll
        for (int j = 0; j < 4; ++j) {
            const int c = n0 + wc * 64 + j * 16 + row16;
            const float bj = be[c];
#pragma unroll
            for (int q2 = 0; q2 < 4; ++q2) {
                const int r = r0 + q2;
                float v = acc[i][j][q2] + bj;
                if (EPI == 0) {
                    if (RELU) v = fmaxf(v, 0.f);
                    oe[(size_t)r * 512 + c] = f2bf(v);
                } else {  // EPI 6
                    const float wrow = (r < N_NODES) ? wcol[(size_t)r * 4 + e] : 0.f;
                    oe[(size_t)r * 512 + c] = f2bf(v * wrow);
                }
            }
        }
    }
}

// ================= encoder/router bf16x3 GEMM (2-phase, proven) =============
// EPI 4: hi/lo bf16 split -> out0/out1 ; EPI 5: out0 fp32
template<int NPASS, int EPI, int NBN>
__global__ __launch_bounds__(256)
void gemm_mfma(const ushort* __restrict__ A0, const ushort* __restrict__ W0,
               const ushort* __restrict__ A1p, const ushort* __restrict__ W1p,
               const ushort* __restrict__ A2p, const ushort* __restrict__ W2p,
               const float* __restrict__ bias,
               void* __restrict__ out0, void* __restrict__ out1, int Ncols)
{
    __shared__ char smem[32768];
    const int tid = threadIdx.x;
    const int w = tid >> 6, lane = tid & 63;

    const int wgid = xcd_swizzle(blockIdx.x, gridDim.x);
    const int m0 = (wgid / NBN) * 128;
    const int n0 = (wgid % NBN) * 128;

    f32x4 acc[4][4];
#pragma unroll
    for (int i = 0; i < 4; ++i)
#pragma unroll
        for (int j = 0; j < 4; ++j) acc[i][j] = (f32x4){0.f, 0.f, 0.f, 0.f};

    const int srow = lane >> 2, schk = lane & 3;
    const int wr = w >> 1, wc = w & 1;
    const int row16 = lane & 15;
    const uint koffB = (uint)(lane >> 4) * 16u;
    const uint aoff0 = (uint)(wr * 64 + row16) * 64u + koffB;
    const uint boff0 = 8192u + (uint)(wc * 64 + row16) * 64u + koffB;

    const int NT = NPASS * 16;
    auto Asel = [&](int t) -> const ushort* { return (t < 16) ? A0 : ((t < 32) ? A1p : A2p); };
    auto Wsel = [&](int t) -> const ushort* { return (t < 16) ? W0 : ((t < 32) ? W1p : W2p); };

    auto stage = [&](int buf, int t) {
        const ushort* __restrict__ A  = Asel(t);
        const ushort* __restrict__ Wt = Wsel(t);
        const int kt = (t & 15) * 32;
        char* base = smem + buf * 16384;
#pragma unroll
        for (int c = 0; c < 2; ++c) {
            const int rb = c * 64 + w * 16;
            async_copy16(A  + (size_t)(m0 + rb + srow) * 512 + kt + schk * 8, base + rb * 64);
            async_copy16(Wt + (size_t)(n0 + rb + srow) * 512 + kt + schk * 8, base + 8192 + rb * 64);
        }
    };
    auto compute = [&](int buf) {
        const char* base = smem + buf * 16384;
        bf16x8 af[4], bfr[4];
#pragma unroll
        for (int i = 0; i < 4; ++i) af[i] = *(const bf16x8*)(base + aoff0 + i * 1024);
#pragma unroll
        for (int j = 0; j < 4; ++j) bfr[j] = *(const bf16x8*)(base + boff0 + j * 1024);
#pragma unroll
        for (int i = 0; i < 4; ++i)
#pragma unroll
            for (int j = 0; j < 4; ++j)
                acc[i][j] = __builtin_amdgcn_mfma_f32_16x16x32_bf16(af[i], bfr[j], acc[i][j], 0, 0, 0);
    };

    stage(0, 0);
    for (int t = 0; t < NT - 1; ++t) {
        stage((t + 1) & 1, t + 1);
        asm volatile("s_waitcnt vmcnt(4)" ::: "memory");
        __builtin_amdgcn_s_barrier();
        compute(t & 1);
        __builtin_amdgcn_s_barrier();
    }
    asm volatile("s_waitcnt vmcnt(0)" ::: "memory");
    __builtin_amdgcn_s_barrier();
    compute((NT - 1) & 1);

#pragma unroll
    for (int i = 0; i < 4; ++i) {
        const int r0 = m0 + wr * 64 + i * 16 + (lane >> 4) * 4;
#pragma unroll
        for (int j = 0; j < 4; ++j) {
            const int c = n0 + wc * 64 + j * 16 + row16;
            const float bj = (EPI == 5) ? 0.f : bias[c];
#pragma unroll
            for (int q2 = 0; q2 < 4; ++q2) {
                const int r = r0 + q2;
                float v = acc[i][j][q2] + bj;
                if (EPI == 4) {
                    const ushort hi = f2bf(v);
                    const ushort lo = f2bf(v - bf2f(hi));
                    ((ushort*)out0)[(size_t)r * Ncols + c] = hi;
                    ((ushort*)out1)[(size_t)r * Ncols + c] = lo;
                } else {
                    ((float*)out0)[(size_t)r * Ncols + c] = v;
                }
            }
        }
    }
}

// out[r,c] = sum_e bf2f(wz[e][r,c])  (wz 4 experts contiguous, 2 cols/thread)
__global__ __launch_bounds__(256)
void reduce_wz_kernel(const uint* __restrict__ wz4, float2* __restrict__ out)
{
    const size_t idx = (size_t)blockIdx.x * 256 + threadIdx.x;  // < N_NODES*256
    const size_t es = (size_t)P_ROWS * 256;  // uints per expert
    const uint a = wz4[idx], b = wz4[idx + es];
    const uint c = wz4[idx + 2 * es], d = wz4[idx + 3 * es];
    float lo = bf2f((ushort)(a & 0xffffu)) + bf2f((ushort)(b & 0xffffu))
             + bf2f((ushort)(c & 0xffffu)) + bf2f((ushort)(d & 0xffffu));
    float hi = bf2f((ushort)(a >> 16)) + bf2f((ushort)(b >> 16))
             + bf2f((ushort)(c >> 16)) + bf2f((ushort)(d >> 16));
    out[idx] = make_float2(lo, hi);
}

// t1 = relu(x[:,4:10] @ enc_W1 + enc_b1), split into bf16 hi+lo; zero pad rows
__global__ void encoder1_kernel(const float* __restrict__ x, const float* __restrict__ W1,
                                const float* __restrict__ b1,
                                ushort* __restrict__ t1hi, ushort* __restrict__ t1lo)
{
    const int idx = blockIdx.x * blockDim.x + threadIdx.x;
    if (idx >= P_ROWS * H_DIM) return;
    const int i = idx / H_DIM, j = idx - i * H_DIM;
    float v = 0.f;
    if (i < N_NODES) {
        const float* xr = &x[i * 16 + 4];
        v = b1[j];
#pragma unroll
        for (int k = 0; k < 6; ++k) v = fmaf(xr[k], W1[k * H_DIM + j], v);
        v = fmaxf(v, 0.f);
    }
    const ushort hi = f2bf(v);
    t1hi[idx] = hi;
    t1lo[idx] = f2bf(v - bf2f(hi));
}

__global__ void zero_ints_kernel(int* __restrict__ p, int n)
{
    const int idx = blockIdx.x * blockDim.x + threadIdx.x;
    if (idx < n) p[idx] = 0;
}

__global__ void graph_bounds_kernel(const int* __restrict__ batch, int* __restrict__ gstart)
{
    const int g = threadIdx.x;
    if (g > G_GRAPHS) return;
    int lo = 0, hi = N_NODES;
    while (lo < hi) {
        const int mid = (lo + hi) >> 1;
        if (batch[mid] < g) lo = mid + 1; else hi = mid;
    }
    gstart[g] = lo;
}

__global__ __launch_bounds__(256)
void edge_hist_kernel(const int* __restrict__ src, const int* __restrict__ dst,
                      const int* __restrict__ batch,
                      int* __restrict__ part, int* __restrict__ deg)
{
    __shared__ int hist[G_GRAPHS];
    const int tid = threadIdx.x;
    if (tid < G_GRAPHS) hist[tid] = 0;
    __syncthreads();
    for (int e = blockIdx.x * 256 + tid; e < N_EDGES; e += EH_BLOCKS * 256) {
        atomicAdd(&deg[dst[e]], 1);
        atomicAdd(&hist[batch[src[e]]], 1);
    }
    __syncthreads();
    if (tid < G_GRAPHS) part[blockIdx.x * G_GRAPHS + tid] = hist[tid];
}

__global__ void stats_finalize_kernel(const int* __restrict__ gstart, const int* __restrict__ part,
                                      float* __restrict__ f_norm, float* __restrict__ size_norm)
{
    const int g = threadIdx.x;  // exactly 64
    const float nn = fmaxf((float)(gstart[g + 1] - gstart[g]), 1.0f);
    int ec = 0;
#pragma unroll 8
    for (int b = 0; b < EH_BLOCKS; ++b) ec += part[b * G_GRAPHS + g];
    const float ee = (float)ec;
    const float ln = logf(nn);
    const float le = log1pf(ee);
    float s0 = ln, s1 = le;
#pragma unroll
    for (int o = 32; o > 0; o >>= 1) { s0 += __shfl_xor(s0, o); s1 += __shfl_xor(s1, o); }
    const float m0 = s0 / 64.f, m1 = s1 / 64.f;
    const float d0 = ln - m0, d1 = le - m1;
    float v0 = d0 * d0, v1 = d1 * d1;
#pragma unroll
    for (int o = 32; o > 0; o >>= 1) { v0 += __shfl_xor(v0, o); v1 += __shfl_xor(v1, o); }
    const float sd0 = sqrtf(v0 / 64.f), sd1 = sqrtf(v1 / 64.f);
    float mn = ln, mx = ln;
#pragma unroll
    for (int o = 32; o > 0; o >>= 1) {
        mn = fminf(mn, __shfl_xor(mn, o));
        mx = fmaxf(mx, __shfl_xor(mx, o));
    }
    f_norm[g * 2 + 0] = d0 / (sd0 + 1e-6f);
    f_norm[g * 2 + 1] = d1 / (sd1 + 1e-6f);
    size_norm[g] = (ln - mn) / (mx - mn + 1e-6f);
}

__global__ void scan_kernel(const int* __restrict__ in, int* __restrict__ row_ptr,
                            int* __restrict__ cursor, int n)
{
    __shared__ int wsum[16];
    __shared__ int carry_s;
    const int tid = threadIdx.x;
    const int lane = tid & 63, wv = tid >> 6;
    if (tid == 0) carry_s = 0;
    __syncthreads();
    for (int base = 0; base < n; base += 1024) {
        const int idx = base + tid;
        const int v = (idx < n) ? in[idx] : 0;
        int x = v;
#pragma unroll
        for (int o = 1; o < 64; o <<= 1) { const int t = __shfl_up(x, o); if (lane >= o) x += t; }
        if (lane == 63) wsum[wv] = x;
        __syncthreads();
        const int carry = carry_s;
        if (wv == 0) {
            int y = (lane < 16) ? wsum[lane] : 0;
#pragma unroll
            for (int o = 1; o < 16; o <<= 1) { const int t = __shfl_up(y, o); if (lane >= o) y += t; }
            if (lane < 16) wsum[lane] = y;
        }
        __syncthreads();
        const int woff = (wv > 0) ? wsum[wv - 1] : 0;
        const int excl = x - v + woff + carry;
        if (idx < n) { row_ptr[idx] = excl; cursor[idx] = excl; }
        __syncthreads();
        if (tid == 0) carry_s = carry + wsum[15];
        __syncthreads();
    }
    if (tid == 0) row_ptr[n] = carry_s;
}

__global__ void scatter_kernel(const int* __restrict__ src, const int* __restrict__ dst,
                               int* __restrict__ cursor, int* __restrict__ csr_col)
{
    const int e = blockIdx.x * blockDim.x + threadIdx.x;
    if (e >= N_EDGES) return;
    const int d = dst[e];
    const int slot = atomicAdd(&cursor[d], 1);
    csr_col[slot] = src[e];
}

__global__ void sort_adj_kernel(const int* __restrict__ row_ptr, int* __restrict__ csr_col)
{
    const int i = blockIdx.x * blockDim.x + threadIdx.x;
    if (i >= N_NODES) return;
    const int b = row_ptr[i], e = row_ptr[i + 1];
    for (int p = b + 1; p < e; ++p) {
        const int key = csr_col[p];
        int q = p - 1;
        while (q >= b && csr_col[q] > key) { csr_col[q + 1] = csr_col[q]; --q; }
        csr_col[q + 1] = key;
    }
}

// agg[e][i,:] = sum over in-edges of z[e][src,:]
// wave-per-node, uint4 (16B/lane) loads; 4 nodes per 256-thr block. (proven)
__global__ __launch_bounds__(256)
void aggregate_bf16(const uint4* __restrict__ z4, const int* __restrict__ row_ptr,
                    const int* __restrict__ csr_col, uint4* __restrict__ agg4)
{
    const size_t es = (size_t)blockIdx.y * P_ROWS * 64;   // uint4s per expert
    const uint4* __restrict__ zz = z4 + es;
    uint4* __restrict__ aa = agg4 + es;
    const int i = blockIdx.x * 4 + (threadIdx.x >> 6);     // node (grid 5000x4 exact)
    const int lane = threadIdx.x & 63;
    const int b = row_ptr[i], e = row_ptr[i + 1];
    float acc[8];
#pragma unroll
    for (int k = 0; k < 8; ++k) acc[k] = 0.f;
    auto add8 = [&](uint4 v) {
        acc[0] += bf2f((ushort)(v.x & 0xffffu)); acc[1] += bf2f((ushort)(v.x >> 16));
        acc[2] += bf2f((ushort)(v.y & 0xffffu)); acc[3] += bf2f((ushort)(v.y >> 16));
        acc[4] += bf2f((ushort)(v.z & 0xffffu)); acc[5] += bf2f((ushort)(v.z >> 16));
        acc[6] += bf2f((ushort)(v.w & 0xffffu)); acc[7] += bf2f((ushort)(v.w >> 16));
    };
    int p = b;
    for (; p + 2 <= e; p += 2) {
        const uint4 v0 = zz[(size_t)csr_col[p] * 64 + lane];
        const uint4 v1 = zz[(size_t)csr_col[p + 1] * 64 + lane];
        add8(v0);
        add8(v1);
    }
    if (p < e) add8(zz[(size_t)csr_col[p] * 64 + lane]);
    uint4 o;
    o.x = (uint)f2bf(acc[0]) | ((uint)f2bf(acc[1]) << 16);
    o.y = (uint)f2bf(acc[2]) | ((uint)f2bf(acc[3]) << 16);
    o.z = (uint)f2bf(acc[4]) | ((uint)f2bf(acc[5]) << 16);
    o.w = (uint)f2bf(acc[6]) | ((uint)f2bf(acc[7]) << 16);
    aa[(size_t)i * 64 + lane] = o;
}

// one 512x512 matrix per blockIdx.z: Wt[n][k] = bf16(W[k][n])
__global__ __launch_bounds__(256)
void transpose_f32_to_bf16(const float* __restrict__ W, ushort* __restrict__ Wt)
{
    __shared__ float tile[32][33];
    const float* Wm = W + (size_t)blockIdx.z * WSZ;
    ushort* Wtm = Wt + (size_t)blockIdx.z * WSZ;
    const int c0 = blockIdx.x * 32, r0 = blockIdx.y * 32;
    const int tc = threadIdx.x & 31, tr = threadIdx.x >> 5;
#pragma unroll
    for (int it = 0; it < 4; ++it)
        tile[tr + it * 8][tc] = Wm[(size_t)(r0 + tr + it * 8) * 512 + c0 + tc];
    __syncthreads();
#pragma unroll
    for (int it = 0; it < 4; ++it) {
        const int cr = tr + it * 8;
        Wtm[(size_t)(c0 + cr) * 512 + r0 + tc] = f2bf(tile[tc][cr]);
    }
}

// W [512][Nin] fp32 -> Wt hi/lo [Nin][512] bf16 (k-stride 512)
__global__ __launch_bounds__(256)
void transpose_split_kernel(const float* __restrict__ W, ushort* __restrict__ Whi,
                            ushort* __restrict__ Wlo, int Nin)
{
    __shared__ float tile[32][33];
    const int c0 = blockIdx.x * 32;
    const int r0 = blockIdx.y * 32;
    const int tc = threadIdx.x & 31, tr = threadIdx.x >> 5;
#pragma unroll
    for (int it = 0; it < 4; ++it)
        tile[tr + it * 8][tc] = W[(size_t)(r0 + tr + it * 8) * Nin + c0 + tc];
    __syncthreads();
#pragma unroll
    for (int it = 0; it < 4; ++it) {
        const int cr = tr + it * 8;
        const float v = tile[tc][cr];
        const ushort hi = f2bf(v);
        Whi[(size_t)(c0 + cr) * 512 + r0 + tc] = hi;
        Wlo[(size_t)(c0 + cr) * 512 + r0 + tc] = f2bf(v - bf2f(hi));
    }
}

// router tail (fp32)
__global__ __launch_bounds__(128)
void router_kernel(const float* __restrict__ rtmp, const int* __restrict__ batch,
                   const float* __restrict__ rW1, const float* __restrict__ rb1,
                   const float* __restrict__ lng, const float* __restrict__ lnb,
                   const float* __restrict__ rW2, const float* __restrict__ rb2,
                   const float* __restrict__ centers,
                   const float* __restrict__ f_norm, const float* __restrict__ size_norm,
                   float* __restrict__ weights)
{
    const int i = blockIdx.x;
    const int j = threadIdx.x;
    const int g = batch[i];
    const float f0 = f_norm[g * 2], f1 = f_norm[g * 2 + 1];
    float r = rtmp[(size_t)i * RH_DIM + j]
            + f0 * rW1[512 * RH_DIM + j] + f1 * rW1[513 * RH_DIM + j] + rb1[j];

    __shared__ float part[2];
    __shared__ float rbuf[RH_DIM];
    __shared__ float lbuf[4];
    const int lane = j & 63, wv = j >> 6;

    float s = r;
#pragma unroll
    for (int o = 32; o > 0; o >>= 1) s += __shfl_xor(s, o);
    if (lane == 0) part[wv] = s;
    __syncthreads();
    const float mean = (part[0] + part[1]) / 128.f;
    __syncthreads();
    const float d = r - mean;
    float v = d * d;
#pragma unroll
    for (int o = 32; o > 0; o >>= 1) v += __shfl_xor(v, o);
    if (lane == 0) part[wv] = v;
    __syncthreads();
    const float var = (part[0] + part[1]) / 128.f;
    const float rn = d / sqrtf(var + 1e-5f) * lng[j] + lnb[j];
    rbuf[j] = fmaxf(rn, 0.f);
    __syncthreads();

    if (j < 4) {
        float acc = rb2[j];
        for (int t = 0; t < RH_DIM; ++t) acc = fmaf(rbuf[t], rW2[t * 4 + j], acc);
        const float sn = size_norm[g];
        const float dd = sn - centers[j];
        lbuf[j] = 0.7f * acc + 0.3f * (-(dd * dd));
    }
    __syncthreads();
    if (j == 0) {
        float p[4];
        const float mx = fmaxf(fmaxf(lbuf[0], lbuf[1]), fmaxf(lbuf[2], lbuf[3]));
#pragma unroll
        for (int c = 0; c < 4; ++c) p[c] = expf(lbuf[c] - mx);
        const float ssum = p[0] + p[1] + p[2] + p[3];
#pragma unroll
        for (int c = 0; c < 4; ++c) p[c] /= ssum;
        int i1 = 0;
#pragma unroll
        for (int c = 1; c < 4; ++c) if (p[c] > p[i1]) i1 = c;
        int i2 = -1;
#pragma unroll
        for (int c = 0; c < 4; ++c) {
            if (c == i1) continue;
            if (i2 < 0 || p[c] > p[i2]) i2 = c;
        }
        const float vs = p[i1] + p[i2] + 1e-8f;
        float wout[4] = {0.f, 0.f, 0.f, 0.f};
        wout[i1] = p[i1] / vs;
        wout[i2] = p[i2] / vs;
#pragma unroll
        for (int c = 0; c < 4; ++c) weights[(size_t)i * 4 + c] = wout[c];
    }
}

extern "C" void kernel_launch(void* const* d_in, const int* in_sizes, int n_in,
                              void* d_out, int out_size, void* d_ws, size_t ws_size,
                              hipStream_t stream)
{
    const float* x       = (const float*)d_in[0];
    const int*   ei      = (const int*)d_in[1];
    const int*   batch   = (const int*)d_in[2];
    const float* enc_W1  = (const float*)d_in[4];
    const float* enc_b1  = (const float*)d_in[5];
    const float* enc_W2  = (const float*)d_in[6];
    const float* enc_b2  = (const float*)d_in[7];
    const float* r_W1    = (const float*)d_in[8];
    const float* r_b1    = (const float*)d_in[9];
    const float* ln_g    = (const float*)d_in[10];
    const float* ln_b    = (const float*)d_in[11];
    const float* r_W2    = (const float*)d_in[12];
    const float* r_b2    = (const float*)d_in[13];
    const float* centers = (const float*)d_in[14];
    const float* W_rel   = (const float*)d_in[15];
    const float* b_rel   = (const float*)d_in[16];
    const float* W_root  = (const float*)d_in[17];
    const int* src = ei;
    const int* dst = ei + N_EDGES;
    float* out = (float*)d_out;

    const size_t PF = (size_t)P_ROWS * H_DIM;
    const size_t PF2 = PF * 2;

    char* wsp = (char*)d_ws;
    size_t off = 0;
    auto alloc = [&](size_t bytes) -> char* {
        char* p = wsp + off;
        off = (off + bytes + 255) & ~(size_t)255;
        return p;
    };
    // region1+region2 contiguous: t1hi|t1lo , h_hi|h_lo -> later wz4 (4 x PF bf16)
    char* region1 = alloc(PF * 4);
    ushort* t1hi = (ushort*)region1;
    ushort* t1lo = (ushort*)(region1 + PF * 2);
    ushort* wz4  = (ushort*)region1;           // spans region1+region2
    char* region2 = alloc(PF * 4);
    ushort* h_hi = (ushort*)region2;
    ushort* h_lo = (ushort*)(region2 + PF * 2);
    // z/agg buffers (pair-wide); rtmp fp32 aliases zA start (dead before expert L0)
    char* B_zA = alloc(PF2 * 2);
    ushort* zAe = (ushort*)B_zA;
    float*  rtmp = (float*)B_zA;
    char* B_zB = alloc(PF2 * 2);
    ushort* zBe = (ushort*)B_zB;
    char* B_ag = alloc(PF2 * 2);
    ushort* agge = (ushort*)B_ag;
    ushort* aggH16 = (ushort*)alloc(PF * 2);
    ushort* Wt_rel16  = (ushort*)alloc((size_t)12 * WSZ * 2);
    ushort* Wt_root16 = (ushort*)alloc((size_t)12 * WSZ * 2);
    ushort* W2t_hi = (ushort*)alloc((size_t)WSZ * 2);
    ushort* W2t_lo = (ushort*)alloc((size_t)WSZ * 2);
    ushort* rW1t_hi = (ushort*)alloc((size_t)128 * 512 * 2);
    ushort* rW1t_lo = (ushort*)alloc((size_t)128 * 512 * 2);
    float*  weights = (float*)alloc((size_t)P_ROWS * 4 * 4);
    int* deg     = (int*)alloc((size_t)N_NODES * 4);
    int* gstart  = (int*)alloc((size_t)(G_GRAPHS + 1) * 4);
    int* part    = (int*)alloc((size_t)EH_BLOCKS * G_GRAPHS * 4);
    int* row_ptr = (int*)alloc((size_t)(N_NODES + 1) * 4);
    int* cursor  = (int*)alloc((size_t)N_NODES * 4);
    int* csr_col = (int*)alloc((size_t)N_EDGES * 4);
    float* f_norm    = (float*)alloc((size_t)G_GRAPHS * 2 * 4);
    float* size_norm = (float*)alloc((size_t)G_GRAPHS * 4);
    (void)in_sizes; (void)n_in; (void)out_size; (void)ws_size;

    const int enc_nwg  = 4 * (P_ROWS / 128);   // 628
    const int rtr_nwg  = 1 * (P_ROWS / 128);   // 157
    const int grp_nwg2 = 8 * (P_ROWS / 128);   // 1256 (pair)
    const dim3 tr_grid(16, 16, 12);
    const dim3 agg_grid1(N_NODES / 4, 1);
    const dim3 agg_grid2(N_NODES / 4, 2);

    // 0) zero deg + one-time weight transposes/splits
    zero_ints_kernel<<<(N_NODES + 255) / 256, 256, 0, stream>>>(deg, N_NODES);
    transpose_f32_to_bf16<<<tr_grid, 256, 0, stream>>>(W_rel, Wt_rel16);
    transpose_f32_to_bf16<<<tr_grid, 256, 0, stream>>>(W_root, Wt_root16);
    transpose_split_kernel<<<dim3(16, 16), 256, 0, stream>>>(enc_W2, W2t_hi, W2t_lo, 512);
    transpose_split_kernel<<<dim3(4, 16), 256, 0, stream>>>(r_W1, rW1t_hi, rW1t_lo, 128);
    // 1) graph stats (contention-free)
    graph_bounds_kernel<<<1, 128, 0, stream>>>(batch, gstart);
    edge_hist_kernel<<<EH_BLOCKS, 256, 0, stream>>>(src, dst, batch, part, deg);
    stats_finalize_kernel<<<1, 64, 0, stream>>>(gstart, part, f_norm, size_norm);
    // 2) encoder: t1 (split) then h = t1@W2 via bf16x3 -> h_hi/h_lo
    encoder1_kernel<<<(P_ROWS * H_DIM + 255) / 256, 256, 0, stream>>>(x, enc_W1, enc_b1, t1hi, t1lo);
    gemm_mfma<3, 4, 4><<<enc_nwg, 256, 0, stream>>>(
        t1hi, W2t_hi, t1hi, W2t_lo, t1lo, W2t_hi, enc_b2, h_hi, h_lo, 512);
    // 3) router: rtmp = h@rW1 via bf16x3 (t1 region dead now)
    gemm_mfma<3, 5, 1><<<rtr_nwg, 256, 0, stream>>>(
        h_hi, rW1t_hi, h_hi, rW1t_lo, h_lo, rW1t_hi, nullptr, rtmp, nullptr, 128);
    router_kernel<<<N_NODES, 128, 0, stream>>>(rtmp, batch, r_W1, r_b1, ln_g, ln_b,
                                               r_W2, r_b2, centers, f_norm, size_norm, weights);
    // 4) CSR build (deterministic: sorted adjacency)
    scan_kernel<<<1, 1024, 0, stream>>>(deg, row_ptr, cursor, N_NODES);
    scatter_kernel<<<(N_EDGES + 255) / 256, 256, 0, stream>>>(src, dst, cursor, csr_col);
    sort_adj_kernel<<<(N_NODES + 255) / 256, 256, 0, stream>>>(row_ptr, csr_col);
    // 5) shared layer-0 aggregation
    aggregate_bf16<<<agg_grid1, 256, 0, stream>>>((const uint4*)h_hi, row_ptr, csr_col,
                                                  (uint4*)aggH16);

    // 6) experts (pair path, proven 128x128 LDS-staged GEMM)
    const size_t WES = (size_t)3 * WSZ;   // expert stride in Wt buffers
    const size_t BES = (size_t)3 * 512;   // expert stride in b_rel
    for (int p = 0; p < 2; ++p) {
        const size_t eb = (size_t)(p * 2);
        const ushort* WrP = Wt_rel16  + eb * WES;
        const ushort* WoP = Wt_root16 + eb * WES;
        const float*  brP = b_rel + eb * BES;
        ushort* wzP = wz4 + eb * PF;
        gemm_grp<true, 0, 2><<<grp_nwg2, 256, 0, stream>>>(
            aggH16, 0, WrP, WES, h_hi, 0, WoP, WES, brP, BES, nullptr, zAe, PF);
        aggregate_bf16<<<agg_grid2, 256, 0, stream>>>((const uint4*)zAe, row_ptr, csr_col,
                                                      (uint4*)agge);
        gemm_grp<true, 0, 2><<<grp_nwg2, 256, 0, stream>>>(
            agge, PF, WrP + WSZ, WES, zAe, PF, WoP + WSZ, WES, brP + 512, BES, nullptr, zBe, PF);
        aggregate_bf16<<<agg_grid2, 256, 0, stream>>>((const uint4*)zBe, row_ptr, csr_col,
                                                      (uint4*)agge);
        gemm_grp<false, 6, 2><<<grp_nwg2, 256, 0, stream>>>(
            agge, PF, WrP + 2 * WSZ, WES, zBe, PF, WoP + 2 * WSZ, WES, brP + 1024, BES,
            weights + eb, wzP, PF);
    }
    // 7) out = sum_e wz[e]
    reduce_wz_kernel<<<N_NODES, 256, 0, stream>>>((const uint*)wz4, (float2*)out);
}

// Round 15
// 767.189 us; speedup vs baseline: 1.1922x; 1.0919x over previous
//
#include <hip/hip_runtime.h>
#include <math.h>

// ---------------- problem constants (match reference) ----------------
#define N_NODES 20000
#define N_EDGES 160000
#define G_GRAPHS 64
#define H_DIM 512
#define RH_DIM 128
#define NE_EXP 4
#define P_ROWS 20096   // 157 * 128, padded row count for GEMM tiles
#define EH_BLOCKS 64   // edge-histogram partial blocks
#define WSZ (512 * 512)

// ================= bf16 helpers =================
typedef __attribute__((ext_vector_type(8))) short bf16x8;
typedef __attribute__((ext_vector_type(4))) float f32x4;

__device__ __forceinline__ ushort f2bf(float f) {
    uint u = __float_as_uint(f);
    return (ushort)((u + 0x7FFFu + ((u >> 16) & 1u)) >> 16);  // round-to-nearest-even
}
__device__ __forceinline__ float bf2f(ushort h) {
    return __uint_as_float(((uint)h) << 16);
}

__device__ __forceinline__ void async_copy16(const void* g, void* l) {
    __builtin_amdgcn_global_load_lds(
        (__attribute__((address_space(1))) void*)g,
        (__attribute__((address_space(3))) void*)l, 16, 0, 0);
}

// ---- T1 bijective XCD swizzle (m204) ----
__device__ __forceinline__ int xcd_swizzle(int orig, int nwg) {
    const int q = nwg >> 3, r = nwg & 7;
    const int xcd = orig & 7, sid = orig >> 3;
    return (xcd < r ? xcd * (q + 1) : r * (q + 1) + (xcd - r) * q) + sid;
}

// ================= grouped expert GEMM (NE2 experts per launch) =============
// PROVEN 2-phase sync skeleton (R4-R14), BK widened 32->64: each barrier
// period stages/computes TWO proven 8KB sub-tiles per operand (row stride
// stays 64B -> identical LDS bank behavior). vmcnt(8) = one stage's loads
// (same counting rule as proven vmcnt(4)). LDS 2 x 32KB = 64KB.
// EPI 0: out bf16(relu?(v+bias)) ; EPI 6: out bf16((v+bias)*wcol[r*4+e])
template<bool RELU, int EPI, int NE2>
__global__ __launch_bounds__(256)
void gemm_grp(const ushort* __restrict__ A1, size_t a1es,
              const ushort* __restrict__ W1, size_t w1es,
              const ushort* __restrict__ A2, size_t a2es,
              const ushort* __restrict__ W2, size_t w2es,
              const float* __restrict__ bias, size_t bes,
              const float* __restrict__ wcol,
              ushort* __restrict__ out0, size_t oes)
{
    __shared__ char smem[65536];   // 2 bufs x (A0 8K | A1 8K | B0 8K | B1 8K)
    const int tid = threadIdx.x;
    const int w = tid >> 6, lane = tid & 63;

    const int wgid = xcd_swizzle(blockIdx.x, gridDim.x);
    const int m0 = (wgid / (4 * NE2)) * 128;
    const int rem = wgid % (4 * NE2);
    const int e  = rem % NE2;
    const int n0 = (rem / NE2) * 128;

    const ushort* __restrict__ A1e = A1 + (size_t)e * a1es;
    const ushort* __restrict__ W1e = W1 + (size_t)e * w1es;
    const ushort* __restrict__ A2e = A2 + (size_t)e * a2es;
    const ushort* __restrict__ W2e = W2 + (size_t)e * w2es;
    const float*  __restrict__ be  = bias + (size_t)e * bes;
    ushort* __restrict__ oe = out0 + (size_t)e * oes;

    f32x4 acc[4][4];
#pragma unroll
    for (int i = 0; i < 4; ++i)
#pragma unroll
        for (int j = 0; j < 4; ++j) acc[i][j] = (f32x4){0.f, 0.f, 0.f, 0.f};

    const int srow = lane >> 2, schk = lane & 3;
    const int wr = w >> 1, wc = w & 1;
    const int row16 = lane & 15;
    const uint koffB = (uint)(lane >> 4) * 16u;
    const uint aoff0 = (uint)(wr * 64 + row16) * 64u + koffB;
    const uint boff0 = 16384u + (uint)(wc * 64 + row16) * 64u + koffB;

    // big tile T = 0..15 covers K columns [ (T&7)*64, (T&7)*64+64 )
    auto stage = [&](int buf, int T) {
        const ushort* __restrict__ A  = (T < 8) ? A1e : A2e;
        const ushort* __restrict__ Wt = (T < 8) ? W1e : W2e;
        const int kt = (T & 7) * 64;
        char* base = smem + buf * 32768;
#pragma unroll
        for (int c = 0; c < 2; ++c) {
            const int rb = c * 64 + w * 16;   // wave-uniform LDS row base
            async_copy16(A  + (size_t)(m0 + rb + srow) * 512 + kt + schk * 8,      base + rb * 64);
            async_copy16(A  + (size_t)(m0 + rb + srow) * 512 + kt + 32 + schk * 8, base + 8192 + rb * 64);
            async_copy16(Wt + (size_t)(n0 + rb + srow) * 512 + kt + schk * 8,      base + 16384 + rb * 64);
            async_copy16(Wt + (size_t)(n0 + rb + srow) * 512 + kt + 32 + schk * 8, base + 24576 + rb * 64);
        }
    };
    auto compute = [&](int buf) {
        const char* base = smem + buf * 32768;
#pragma unroll
        for (int h = 0; h < 2; ++h) {
            bf16x8 af[4], bfr[4];
#pragma unroll
            for (int i = 0; i < 4; ++i) af[i] = *(const bf16x8*)(base + h * 8192 + aoff0 + i * 1024);
#pragma unroll
            for (int j = 0; j < 4; ++j) bfr[j] = *(const bf16x8*)(base + h * 8192 + boff0 + j * 1024);
#pragma unroll
            for (int i = 0; i < 4; ++i)
#pragma unroll
                for (int j = 0; j < 4; ++j)
                    acc[i][j] = __builtin_amdgcn_mfma_f32_16x16x32_bf16(af[i], bfr[j], acc[i][j], 0, 0, 0);
        }
    };

    // 2-phase pipeline (proven skeleton; 16 big tiles)
    stage(0, 0);
    for (int t = 0; t < 15; ++t) {
        stage((t + 1) & 1, t + 1);
        asm volatile("s_waitcnt vmcnt(8)" ::: "memory");
        __builtin_amdgcn_s_barrier();
        compute(t & 1);
        __builtin_amdgcn_s_barrier();
    }
    asm volatile("s_waitcnt vmcnt(0)" ::: "memory");
    __builtin_amdgcn_s_barrier();
    compute(1);

    // epilogue: C/D layout col = lane&15, row = (lane>>4)*4 + q
#pragma unroll
    for (int i = 0; i < 4; ++i) {
        const int r0 = m0 + wr * 64 + i * 16 + (lane >> 4) * 4;
#pragma unroll
        for (int j = 0; j < 4; ++j) {
            const int c = n0 + wc * 64 + j * 16 + row16;
            const float bj = be[c];
#pragma unroll
            for (int q2 = 0; q2 < 4; ++q2) {
                const int r = r0 + q2;
                float v = acc[i][j][q2] + bj;
                if (EPI == 0) {
                    if (RELU) v = fmaxf(v, 0.f);
                    oe[(size_t)r * 512 + c] = f2bf(v);
                } else {  // EPI 6
                    const float wrow = (r < N_NODES) ? wcol[(size_t)r * 4 + e] : 0.f;
                    oe[(size_t)r * 512 + c] = f2bf(v * wrow);
                }
            }
        }
    }
}

// ================= encoder/router bf16x3 GEMM (same BK=64 treatment) ========
// EPI 4: hi/lo bf16 split -> out0/out1 ; EPI 5: out0 fp32
template<int NPASS, int EPI, int NBN>
__global__ __launch_bounds__(256)
void gemm_mfma(const ushort* __restrict__ A0, const ushort* __restrict__ W0,
               const ushort* __restrict__ A1p, const ushort* __restrict__ W1p,
               const ushort* __restrict__ A2p, const ushort* __restrict__ W2p,
               const float* __restrict__ bias,
               void* __restrict__ out0, void* __restrict__ out1, int Ncols)
{
    __shared__ char smem[65536];
    const int tid = threadIdx.x;
    const int w = tid >> 6, lane = tid & 63;

    const int wgid = xcd_swizzle(blockIdx.x, gridDim.x);
    const int m0 = (wgid / NBN) * 128;
    const int n0 = (wgid % NBN) * 128;

    f32x4 acc[4][4];
#pragma unroll
    for (int i = 0; i < 4; ++i)
#pragma unroll
        for (int j = 0; j < 4; ++j) acc[i][j] = (f32x4){0.f, 0.f, 0.f, 0.f};

    const int srow = lane >> 2, schk = lane & 3;
    const int wr = w >> 1, wc = w & 1;
    const int row16 = lane & 15;
    const uint koffB = (uint)(lane >> 4) * 16u;
    const uint aoff0 = (uint)(wr * 64 + row16) * 64u + koffB;
    const uint boff0 = 16384u + (uint)(wc * 64 + row16) * 64u + koffB;

    const int NTT = NPASS * 8;   // big tiles (BK=64)
    auto Asel = [&](int T) -> const ushort* { return (T < 8) ? A0 : ((T < 16) ? A1p : A2p); };
    auto Wsel = [&](int T) -> const ushort* { return (T < 8) ? W0 : ((T < 16) ? W1p : W2p); };

    auto stage = [&](int buf, int T) {
        const ushort* __restrict__ A  = Asel(T);
        const ushort* __restrict__ Wt = Wsel(T);
        const int kt = (T & 7) * 64;
        char* base = smem + buf * 32768;
#pragma unroll
        for (int c = 0; c < 2; ++c) {
            const int rb = c * 64 + w * 16;
            async_copy16(A  + (size_t)(m0 + rb + srow) * 512 + kt + schk * 8,      base + rb * 64);
            async_copy16(A  + (size_t)(m0 + rb + srow) * 512 + kt + 32 + schk * 8, base + 8192 + rb * 64);
            async_copy16(Wt + (size_t)(n0 + rb + srow) * 512 + kt + schk * 8,      base + 16384 + rb * 64);
            async_copy16(Wt + (size_t)(n0 + rb + srow) * 512 + kt + 32 + schk * 8, base + 24576 + rb * 64);
        }
    };
    auto compute = [&](int buf) {
        const char* base = smem + buf * 32768;
#pragma unroll
        for (int h = 0; h < 2; ++h) {
            bf16x8 af[4], bfr[4];
#pragma unroll
            for (int i = 0; i < 4; ++i) af[i] = *(const bf16x8*)(base + h * 8192 + aoff0 + i * 1024);
#pragma unroll
            for (int j = 0; j < 4; ++j) bfr[j] = *(const bf16x8*)(base + h * 8192 + boff0 + j * 1024);
#pragma unroll
            for (int i = 0; i < 4; ++i)
#pragma unroll
                for (int j = 0; j < 4; ++j)
                    acc[i][j] = __builtin_amdgcn_mfma_f32_16x16x32_bf16(af[i], bfr[j], acc[i][j], 0, 0, 0);
        }
    };

    stage(0, 0);
    for (int t = 0; t < NTT - 1; ++t) {
        stage((t + 1) & 1, t + 1);
        asm volatile("s_waitcnt vmcnt(8)" ::: "memory");
        __builtin_amdgcn_s_barrier();
        compute(t & 1);
        __builtin_amdgcn_s_barrier();
    }
    asm volatile("s_waitcnt vmcnt(0)" ::: "memory");
    __builtin_amdgcn_s_barrier();
    compute((NTT - 1) & 1);

#pragma unroll
    for (int i = 0; i < 4; ++i) {
        const int r0 = m0 + wr * 64 + i * 16 + (lane >> 4) * 4;
#pragma unroll
        for (int j = 0; j < 4; ++j) {
            const int c = n0 + wc * 64 + j * 16 + row16;
            const float bj = (EPI == 5) ? 0.f : bias[c];
#pragma unroll
            for (int q2 = 0; q2 < 4; ++q2) {
                const int r = r0 + q2;
                float v = acc[i][j][q2] + bj;
                if (EPI == 4) {
                    const ushort hi = f2bf(v);
                    const ushort lo = f2bf(v - bf2f(hi));
                    ((ushort*)out0)[(size_t)r * Ncols + c] = hi;
                    ((ushort*)out1)[(size_t)r * Ncols + c] = lo;
                } else {
                    ((float*)out0)[(size_t)r * Ncols + c] = v;
                }
            }
        }
    }
}

// out[r,c] = sum_e bf2f(wz[e][r,c])  (wz 4 experts contiguous, 2 cols/thread)
__global__ __launch_bounds__(256)
void reduce_wz_kernel(const uint* __restrict__ wz4, float2* __restrict__ out)
{
    const size_t idx = (size_t)blockIdx.x * 256 + threadIdx.x;  // < N_NODES*256
    const size_t es = (size_t)P_ROWS * 256;  // uints per expert
    const uint a = wz4[idx], b = wz4[idx + es];
    const uint c = wz4[idx + 2 * es], d = wz4[idx + 3 * es];
    float lo = bf2f((ushort)(a & 0xffffu)) + bf2f((ushort)(b & 0xffffu))
             + bf2f((ushort)(c & 0xffffu)) + bf2f((ushort)(d & 0xffffu));
    float hi = bf2f((ushort)(a >> 16)) + bf2f((ushort)(b >> 16))
             + bf2f((ushort)(c >> 16)) + bf2f((ushort)(d >> 16));
    out[idx] = make_float2(lo, hi);
}

// t1 = relu(x[:,4:10] @ enc_W1 + enc_b1), split into bf16 hi+lo; zero pad rows
__global__ void encoder1_kernel(const float* __restrict__ x, const float* __restrict__ W1,
                                const float* __restrict__ b1,
                                ushort* __restrict__ t1hi, ushort* __restrict__ t1lo)
{
    const int idx = blockIdx.x * blockDim.x + threadIdx.x;
    if (idx >= P_ROWS * H_DIM) return;
    const int i = idx / H_DIM, j = idx - i * H_DIM;
    float v = 0.f;
    if (i < N_NODES) {
        const float* xr = &x[i * 16 + 4];
        v = b1[j];
#pragma unroll
        for (int k = 0; k < 6; ++k) v = fmaf(xr[k], W1[k * H_DIM + j], v);
        v = fmaxf(v, 0.f);
    }
    const ushort hi = f2bf(v);
    t1hi[idx] = hi;
    t1lo[idx] = f2bf(v - bf2f(hi));
}

__global__ void zero_ints_kernel(int* __restrict__ p, int n)
{
    const int idx = blockIdx.x * blockDim.x + threadIdx.x;
    if (idx < n) p[idx] = 0;
}

__global__ void graph_bounds_kernel(const int* __restrict__ batch, int* __restrict__ gstart)
{
    const int g = threadIdx.x;
    if (g > G_GRAPHS) return;
    int lo = 0, hi = N_NODES;
    while (lo < hi) {
        const int mid = (lo + hi) >> 1;
        if (batch[mid] < g) lo = mid + 1; else hi = mid;
    }
    gstart[g] = lo;
}

__global__ __launch_bounds__(256)
void edge_hist_kernel(const int* __restrict__ src, const int* __restrict__ dst,
                      const int* __restrict__ batch,
                      int* __restrict__ part, int* __restrict__ deg)
{
    __shared__ int hist[G_GRAPHS];
    const int tid = threadIdx.x;
    if (tid < G_GRAPHS) hist[tid] = 0;
    __syncthreads();
    for (int e = blockIdx.x * 256 + tid; e < N_EDGES; e += EH_BLOCKS * 256) {
        atomicAdd(&deg[dst[e]], 1);
        atomicAdd(&hist[batch[src[e]]], 1);
    }
    __syncthreads();
    if (tid < G_GRAPHS) part[blockIdx.x * G_GRAPHS + tid] = hist[tid];
}

__global__ void stats_finalize_kernel(const int* __restrict__ gstart, const int* __restrict__ part,
                                      float* __restrict__ f_norm, float* __restrict__ size_norm)
{
    const int g = threadIdx.x;  // exactly 64
    const float nn = fmaxf((float)(gstart[g + 1] - gstart[g]), 1.0f);
    int ec = 0;
#pragma unroll 8
    for (int b = 0; b < EH_BLOCKS; ++b) ec += part[b * G_GRAPHS + g];
    const float ee = (float)ec;
    const float ln = logf(nn);
    const float le = log1pf(ee);
    float s0 = ln, s1 = le;
#pragma unroll
    for (int o = 32; o > 0; o >>= 1) { s0 += __shfl_xor(s0, o); s1 += __shfl_xor(s1, o); }
    const float m0 = s0 / 64.f, m1 = s1 / 64.f;
    const float d0 = ln - m0, d1 = le - m1;
    float v0 = d0 * d0, v1 = d1 * d1;
#pragma unroll
    for (int o = 32; o > 0; o >>= 1) { v0 += __shfl_xor(v0, o); v1 += __shfl_xor(v1, o); }
    const float sd0 = sqrtf(v0 / 64.f), sd1 = sqrtf(v1 / 64.f);
    float mn = ln, mx = ln;
#pragma unroll
    for (int o = 32; o > 0; o >>= 1) {
        mn = fminf(mn, __shfl_xor(mn, o));
        mx = fmaxf(mx, __shfl_xor(mx, o));
    }
    f_norm[g * 2 + 0] = d0 / (sd0 + 1e-6f);
    f_norm[g * 2 + 1] = d1 / (sd1 + 1e-6f);
    size_norm[g] = (ln - mn) / (mx - mn + 1e-6f);
}

__global__ void scan_kernel(const int* __restrict__ in, int* __restrict__ row_ptr,
                            int* __restrict__ cursor, int n)
{
    __shared__ int wsum[16];
    __shared__ int carry_s;
    const int tid = threadIdx.x;
    const int lane = tid & 63, wv = tid >> 6;
    if (tid == 0) carry_s = 0;
    __syncthreads();
    for (int base = 0; base < n; base += 1024) {
        const int idx = base + tid;
        const int v = (idx < n) ? in[idx] : 0;
        int x = v;
#pragma unroll
        for (int o = 1; o < 64; o <<= 1) { const int t = __shfl_up(x, o); if (lane >= o) x += t; }
        if (lane == 63) wsum[wv] = x;
        __syncthreads();
        const int carry = carry_s;
        if (wv == 0) {
            int y = (lane < 16) ? wsum[lane] : 0;
#pragma unroll
            for (int o = 1; o < 16; o <<= 1) { const int t = __shfl_up(y, o); if (lane >= o) y += t; }
            if (lane < 16) wsum[lane] = y;
        }
        __syncthreads();
        const int woff = (wv > 0) ? wsum[wv - 1] : 0;
        const int excl = x - v + woff + carry;
        if (idx < n) { row_ptr[idx] = excl; cursor[idx] = excl; }
        __syncthreads();
        if (tid == 0) carry_s = carry + wsum[15];
        __syncthreads();
    }
    if (tid == 0) row_ptr[n] = carry_s;
}

__global__ void scatter_kernel(const int* __restrict__ src, const int* __restrict__ dst,
                               int* __restrict__ cursor, int* __restrict__ csr_col)
{
    const int e = blockIdx.x * blockDim.x + threadIdx.x;
    if (e >= N_EDGES) return;
    const int d = dst[e];
    const int slot = atomicAdd(&cursor[d], 1);
    csr_col[slot] = src[e];
}

__global__ void sort_adj_kernel(const int* __restrict__ row_ptr, int* __restrict__ csr_col)
{
    const int i = blockIdx.x * blockDim.x + threadIdx.x;
    if (i >= N_NODES) return;
    const int b = row_ptr[i], e = row_ptr[i + 1];
    for (int p = b + 1; p < e; ++p) {
        const int key = csr_col[p];
        int q = p - 1;
        while (q >= b && csr_col[q] > key) { csr_col[q + 1] = csr_col[q]; --q; }
        csr_col[q + 1] = key;
    }
}

// agg[e][i,:] = sum over in-edges of z[e][src,:]
// wave-per-node, uint4 (16B/lane) loads; 4 nodes per 256-thr block. (proven)
__global__ __launch_bounds__(256)
void aggregate_bf16(const uint4* __restrict__ z4, const int* __restrict__ row_ptr,
                    const int* __restrict__ csr_col, uint4* __restrict__ agg4)
{
    const size_t es = (size_t)blockIdx.y * P_ROWS * 64;   // uint4s per expert
    const uint4* __restrict__ zz = z4 + es;
    uint4* __restrict__ aa = agg4 + es;
    const int i = blockIdx.x * 4 + (threadIdx.x >> 6);     // node (grid 5000x4 exact)
    const int lane = threadIdx.x & 63;
    const int b = row_ptr[i], e = row_ptr[i + 1];
    float acc[8];
#pragma unroll
    for (int k = 0; k < 8; ++k) acc[k] = 0.f;
    auto add8 = [&](uint4 v) {
        acc[0] += bf2f((ushort)(v.x & 0xffffu)); acc[1] += bf2f((ushort)(v.x >> 16));
        acc[2] += bf2f((ushort)(v.y & 0xffffu)); acc[3] += bf2f((ushort)(v.y >> 16));
        acc[4] += bf2f((ushort)(v.z & 0xffffu)); acc[5] += bf2f((ushort)(v.z >> 16));
        acc[6] += bf2f((ushort)(v.w & 0xffffu)); acc[7] += bf2f((ushort)(v.w >> 16));
    };
    int p = b;
    for (; p + 2 <= e; p += 2) {
        const uint4 v0 = zz[(size_t)csr_col[p] * 64 + lane];
        const uint4 v1 = zz[(size_t)csr_col[p + 1] * 64 + lane];
        add8(v0);
        add8(v1);
    }
    if (p < e) add8(zz[(size_t)csr_col[p] * 64 + lane]);
    uint4 o;
    o.x = (uint)f2bf(acc[0]) | ((uint)f2bf(acc[1]) << 16);
    o.y = (uint)f2bf(acc[2]) | ((uint)f2bf(acc[3]) << 16);
    o.z = (uint)f2bf(acc[4]) | ((uint)f2bf(acc[5]) << 16);
    o.w = (uint)f2bf(acc[6]) | ((uint)f2bf(acc[7]) << 16);
    aa[(size_t)i * 64 + lane] = o;
}

// one 512x512 matrix per blockIdx.z: Wt[n][k] = bf16(W[k][n])
__global__ __launch_bounds__(256)
void transpose_f32_to_bf16(const float* __restrict__ W, ushort* __restrict__ Wt)
{
    __shared__ float tile[32][33];
    const float* Wm = W + (size_t)blockIdx.z * WSZ;
    ushort* Wtm = Wt + (size_t)blockIdx.z * WSZ;
    const int c0 = blockIdx.x * 32, r0 = blockIdx.y * 32;
    const int tc = threadIdx.x & 31, tr = threadIdx.x >> 5;
#pragma unroll
    for (int it = 0; it < 4; ++it)
        tile[tr + it * 8][tc] = Wm[(size_t)(r0 + tr + it * 8) * 512 + c0 + tc];
    __syncthreads();
#pragma unroll
    for (int it = 0; it < 4; ++it) {
        const int cr = tr + it * 8;
        Wtm[(size_t)(c0 + cr) * 512 + r0 + tc] = f2bf(tile[tc][cr]);
    }
}

// W [512][Nin] fp32 -> Wt hi/lo [Nin][512] bf16 (k-stride 512)
__global__ __launch_bounds__(256)
void transpose_split_kernel(const float* __restrict__ W, ushort* __restrict__ Whi,
                            ushort* __restrict__ Wlo, int Nin)
{
    __shared__ float tile[32][33];
    const int c0 = blockIdx.x * 32;
    const int r0 = blockIdx.y * 32;
    const int tc = threadIdx.x & 31, tr = threadIdx.x >> 5;
#pragma unroll
    for (int it = 0; it < 4; ++it)
        tile[tr + it * 8][tc] = W[(size_t)(r0 + tr + it * 8) * Nin + c0 + tc];
    __syncthreads();
#pragma unroll
    for (int it = 0; it < 4; ++it) {
        const int cr = tr + it * 8;
        const float v = tile[tc][cr];
        const ushort hi = f2bf(v);
        Whi[(size_t)(c0 + cr) * 512 + r0 + tc] = hi;
        Wlo[(size_t)(c0 + cr) * 512 + r0 + tc] = f2bf(v - bf2f(hi));
    }
}

// router tail (fp32)
__global__ __launch_bounds__(128)
void router_kernel(const float* __restrict__ rtmp, const int* __restrict__ batch,
                   const float* __restrict__ rW1, const float* __restrict__ rb1,
                   const float* __restrict__ lng, const float* __restrict__ lnb,
                   const float* __restrict__ rW2, const float* __restrict__ rb2,
                   const float* __restrict__ centers,
                   const float* __restrict__ f_norm, const float* __restrict__ size_norm,
                   float* __restrict__ weights)
{
    const int i = blockIdx.x;
    const int j = threadIdx.x;
    const int g = batch[i];
    const float f0 = f_norm[g * 2], f1 = f_norm[g * 2 + 1];
    float r = rtmp[(size_t)i * RH_DIM + j]
            + f0 * rW1[512 * RH_DIM + j] + f1 * rW1[513 * RH_DIM + j] + rb1[j];

    __shared__ float part[2];
    __shared__ float rbuf[RH_DIM];
    __shared__ float lbuf[4];
    const int lane = j & 63, wv = j >> 6;

    float s = r;
#pragma unroll
    for (int o = 32; o > 0; o >>= 1) s += __shfl_xor(s, o);
    if (lane == 0) part[wv] = s;
    __syncthreads();
    const float mean = (part[0] + part[1]) / 128.f;
    __syncthreads();
    const float d = r - mean;
    float v = d * d;
#pragma unroll
    for (int o = 32; o > 0; o >>= 1) v += __shfl_xor(v, o);
    if (lane == 0) part[wv] = v;
    __syncthreads();
    const float var = (part[0] + part[1]) / 128.f;
    const float rn = d / sqrtf(var + 1e-5f) * lng[j] + lnb[j];
    rbuf[j] = fmaxf(rn, 0.f);
    __syncthreads();

    if (j < 4) {
        float acc = rb2[j];
        for (int t = 0; t < RH_DIM; ++t) acc = fmaf(rbuf[t], rW2[t * 4 + j], acc);
        const float sn = size_norm[g];
        const float dd = sn - centers[j];
        lbuf[j] = 0.7f * acc + 0.3f * (-(dd * dd));
    }
    __syncthreads();
    if (j == 0) {
        float p[4];
        const float mx = fmaxf(fmaxf(lbuf[0], lbuf[1]), fmaxf(lbuf[2], lbuf[3]));
#pragma unroll
        for (int c = 0; c < 4; ++c) p[c] = expf(lbuf[c] - mx);
        const float ssum = p[0] + p[1] + p[2] + p[3];
#pragma unroll
        for (int c = 0; c < 4; ++c) p[c] /= ssum;
        int i1 = 0;
#pragma unroll
        for (int c = 1; c < 4; ++c) if (p[c] > p[i1]) i1 = c;
        int i2 = -1;
#pragma unroll
        for (int c = 0; c < 4; ++c) {
            if (c == i1) continue;
            if (i2 < 0 || p[c] > p[i2]) i2 = c;
        }
        const float vs = p[i1] + p[i2] + 1e-8f;
        float wout[4] = {0.f, 0.f, 0.f, 0.f};
        wout[i1] = p[i1] / vs;
        wout[i2] = p[i2] / vs;
#pragma unroll
        for (int c = 0; c < 4; ++c) weights[(size_t)i * 4 + c] = wout[c];
    }
}

extern "C" void kernel_launch(void* const* d_in, const int* in_sizes, int n_in,
                              void* d_out, int out_size, void* d_ws, size_t ws_size,
                              hipStream_t stream)
{
    const float* x       = (const float*)d_in[0];
    const int*   ei      = (const int*)d_in[1];
    const int*   batch   = (const int*)d_in[2];
    const float* enc_W1  = (const float*)d_in[4];
    const float* enc_b1  = (const float*)d_in[5];
    const float* enc_W2  = (const float*)d_in[6];
    const float* enc_b2  = (const float*)d_in[7];
    const float* r_W1    = (const float*)d_in[8];
    const float* r_b1    = (const float*)d_in[9];
    const float* ln_g    = (const float*)d_in[10];
    const float* ln_b    = (const float*)d_in[11];
    const float* r_W2    = (const float*)d_in[12];
    const float* r_b2    = (const float*)d_in[13];
    const float* centers = (const float*)d_in[14];
    const float* W_rel   = (const float*)d_in[15];
    const float* b_rel   = (const float*)d_in[16];
    const float* W_root  = (const float*)d_in[17];
    const int* src = ei;
    const int* dst = ei + N_EDGES;
    float* out = (float*)d_out;

    const size_t PF = (size_t)P_ROWS * H_DIM;
    const size_t PF2 = PF * 2;

    char* wsp = (char*)d_ws;
    size_t off = 0;
    auto alloc = [&](size_t bytes) -> char* {
        char* p = wsp + off;
        off = (off + bytes + 255) & ~(size_t)255;
        return p;
    };
    // region1+region2 contiguous: t1hi|t1lo , h_hi|h_lo -> later wz4 (4 x PF bf16)
    char* region1 = alloc(PF * 4);
    ushort* t1hi = (ushort*)region1;
    ushort* t1lo = (ushort*)(region1 + PF * 2);
    ushort* wz4  = (ushort*)region1;           // spans region1+region2
    char* region2 = alloc(PF * 4);
    ushort* h_hi = (ushort*)region2;
    ushort* h_lo = (ushort*)(region2 + PF * 2);
    // z/agg buffers (pair-wide); rtmp fp32 aliases zA start (dead before expert L0)
    char* B_zA = alloc(PF2 * 2);
    ushort* zAe = (ushort*)B_zA;
    float*  rtmp = (float*)B_zA;
    char* B_zB = alloc(PF2 * 2);
    ushort* zBe = (ushort*)B_zB;
    char* B_ag = alloc(PF2 * 2);
    ushort* agge = (ushort*)B_ag;
    ushort* aggH16 = (ushort*)alloc(PF * 2);
    ushort* Wt_rel16  = (ushort*)alloc((size_t)12 * WSZ * 2);
    ushort* Wt_root16 = (ushort*)alloc((size_t)12 * WSZ * 2);
    ushort* W2t_hi = (ushort*)alloc((size_t)WSZ * 2);
    ushort* W2t_lo = (ushort*)alloc((size_t)WSZ * 2);
    ushort* rW1t_hi = (ushort*)alloc((size_t)128 * 512 * 2);
    ushort* rW1t_lo = (ushort*)alloc((size_t)128 * 512 * 2);
    float*  weights = (float*)alloc((size_t)P_ROWS * 4 * 4);
    int* deg     = (int*)alloc((size_t)N_NODES * 4);
    int* gstart  = (int*)alloc((size_t)(G_GRAPHS + 1) * 4);
    int* part    = (int*)alloc((size_t)EH_BLOCKS * G_GRAPHS * 4);
    int* row_ptr = (int*)alloc((size_t)(N_NODES + 1) * 4);
    int* cursor  = (int*)alloc((size_t)N_NODES * 4);
    int* csr_col = (int*)alloc((size_t)N_EDGES * 4);
    float* f_norm    = (float*)alloc((size_t)G_GRAPHS * 2 * 4);
    float* size_norm = (float*)alloc((size_t)G_GRAPHS * 4);
    (void)in_sizes; (void)n_in; (void)out_size; (void)ws_size;

    const int enc_nwg  = 4 * (P_ROWS / 128);   // 628
    const int rtr_nwg  = 1 * (P_ROWS / 128);   // 157
    const int grp_nwg2 = 8 * (P_ROWS / 128);   // 1256 (pair)
    const dim3 tr_grid(16, 16, 12);
    const dim3 agg_grid1(N_NODES / 4, 1);
    const dim3 agg_grid2(N_NODES / 4, 2);

    // 0) zero deg + one-time weight transposes/splits
    zero_ints_kernel<<<(N_NODES + 255) / 256, 256, 0, stream>>>(deg, N_NODES);
    transpose_f32_to_bf16<<<tr_grid, 256, 0, stream>>>(W_rel, Wt_rel16);
    transpose_f32_to_bf16<<<tr_grid, 256, 0, stream>>>(W_root, Wt_root16);
    transpose_split_kernel<<<dim3(16, 16), 256, 0, stream>>>(enc_W2, W2t_hi, W2t_lo, 512);
    transpose_split_kernel<<<dim3(4, 16), 256, 0, stream>>>(r_W1, rW1t_hi, rW1t_lo, 128);
    // 1) graph stats (contention-free)
    graph_bounds_kernel<<<1, 128, 0, stream>>>(batch, gstart);
    edge_hist_kernel<<<EH_BLOCKS, 256, 0, stream>>>(src, dst, batch, part, deg);
    stats_finalize_kernel<<<1, 64, 0, stream>>>(gstart, part, f_norm, size_norm);
    // 2) encoder: t1 (split) then h = t1@W2 via bf16x3 -> h_hi/h_lo
    encoder1_kernel<<<(P_ROWS * H_DIM + 255) / 256, 256, 0, stream>>>(x, enc_W1, enc_b1, t1hi, t1lo);
    gemm_mfma<3, 4, 4><<<enc_nwg, 256, 0, stream>>>(
        t1hi, W2t_hi, t1hi, W2t_lo, t1lo, W2t_hi, enc_b2, h_hi, h_lo, 512);
    // 3) router: rtmp = h@rW1 via bf16x3 (t1 region dead now)
    gemm_mfma<3, 5, 1><<<rtr_nwg, 256, 0, stream>>>(
        h_hi, rW1t_hi, h_hi, rW1t_lo, h_lo, rW1t_hi, nullptr, rtmp, nullptr, 128);
    router_kernel<<<N_NODES, 128, 0, stream>>>(rtmp, batch, r_W1, r_b1, ln_g, ln_b,
                                               r_W2, r_b2, centers, f_norm, size_norm, weights);
    // 4) CSR build (deterministic: sorted adjacency)
    scan_kernel<<<1, 1024, 0, stream>>>(deg, row_ptr, cursor, N_NODES);
    scatter_kernel<<<(N_EDGES + 255) / 256, 256, 0, stream>>>(src, dst, cursor, csr_col);
    sort_adj_kernel<<<(N_NODES + 255) / 256, 256, 0, stream>>>(row_ptr, csr_col);
    // 5) shared layer-0 aggregation
    aggregate_bf16<<<agg_grid1, 256, 0, stream>>>((const uint4*)h_hi, row_ptr, csr_col,
                                                  (uint4*)aggH16);

    // 6) experts (pair path, BK=64 2-phase GEMM)
    const size_t WES = (size_t)3 * WSZ;   // expert stride in Wt buffers
    const size_t BES = (size_t)3 * 512;   // expert stride in b_rel
    for (int p = 0; p < 2; ++p) {
        const size_t eb = (size_t)(p * 2);
        const ushort* WrP = Wt_rel16  + eb * WES;
        const ushort* WoP = Wt_root16 + eb * WES;
        const float*  brP = b_rel + eb * BES;
        ushort* wzP = wz4 + eb * PF;
        gemm_grp<true, 0, 2><<<grp_nwg2, 256, 0, stream>>>(
            aggH16, 0, WrP, WES, h_hi, 0, WoP, WES, brP, BES, nullptr, zAe, PF);
        aggregate_bf16<<<agg_grid2, 256, 0, stream>>>((const uint4*)zAe, row_ptr, csr_col,
                                                      (uint4*)agge);
        gemm_grp<true, 0, 2><<<grp_nwg2, 256, 0, stream>>>(
            agge, PF, WrP + WSZ, WES, zAe, PF, WoP + WSZ, WES, brP + 512, BES, nullptr, zBe, PF);
        aggregate_bf16<<<agg_grid2, 256, 0, stream>>>((const uint4*)zBe, row_ptr, csr_col,
                                                      (uint4*)agge);
        gemm_grp<false, 6, 2><<<grp_nwg2, 256, 0, stream>>>(
            agge, PF, WrP + 2 * WSZ, WES, zBe, PF, WoP + 2 * WSZ, WES, brP + 1024, BES,
            weights + eb, wzP, PF);
    }
    // 7) out = sum_e wz[e]
    reduce_wz_kernel<<<N_NODES, 256, 0, stream>>>((const uint*)wz4, (float2*)out);
}